// Round 3
// baseline (17287.521 us; speedup 1.0000x reference)
//
#include <hip/hip_runtime.h>
#include <hip/hip_cooperative_groups.h>
#include <math.h>

namespace cg = cooperative_groups;

#define En 256
#define Hn 512
#define Bn 64
#define Sn 40
#define Tn 40
#define VTn 32000
#define Rn (Tn*Bn)
#define NCH 500   // 32000 / 64 stat chunks

typedef short v8s __attribute__((ext_vector_type(8)));
typedef float v4f __attribute__((ext_vector_type(4)));

__device__ __forceinline__ float dot4(float4 a, float4 b){
  return a.x*b.x + a.y*b.y + a.z*b.z + a.w*b.w;
}
__device__ __forceinline__ float sigm(float x){ return 1.f/(1.f+__expf(-x)); }
__device__ __forceinline__ unsigned short f2bf(float f){
  unsigned u = __float_as_uint(f);
  unsigned r = u + 0x7FFFu + ((u>>16)&1u);
  return (unsigned short)(r>>16);
}

__global__ void zero_f4(float4* p, int n4){
  int i = blockIdx.x*blockDim.x+threadIdx.x;
  if (i<n4) p[i]=make_float4(0.f,0.f,0.f,0.f);
}

__global__ void build_maps(const int* __restrict__ src, const int* __restrict__ tgt,
                           const int* __restrict__ lens, int* __restrict__ grev,
                           int* __restrict__ gtgt){
  int r = blockIdx.x*blockDim.x+threadIdx.x;
  if (r >= Bn*Sn) return;
  int b = r / Sn, s = r % Sn;
  int j = lens[b]-1-s;
  grev[r] = (j>=0) ? src[b*Sn+j] : -1;
  int t2 = r >> 6, b2 = r & 63;   // Rn == Bn*Sn == 2560
  gtgt[r] = tgt[b2*Tn + t2];
}

// C[M,N] = gatherRows(A)[M,lda] @ B[N,ldb]^T + bias ; 128x128 tiles, BK=8
__global__ __launch_bounds__(256) void gemm128(const float* __restrict__ A, int lda,
                                               const int* __restrict__ gather,
                                               const float* __restrict__ B, int ldb,
                                               const float* __restrict__ bias,
                                               float* __restrict__ C, int ldc, int K){
  __shared__ float As[8][128];
  __shared__ float Bs[8][128];
  const int n0 = blockIdx.x*128, r0 = blockIdx.y*128;
  const int tid = threadIdx.x;
  const int tx = tid & 15, ty = tid >> 4;
  const int lm = tid >> 1, lk = (tid & 1)*4;
  int ar = gather ? gather[r0+lm] : (r0+lm);
  const float* Arow = (ar>=0) ? (A + (size_t)ar*lda + lk) : nullptr;
  const float* Brow = B + (size_t)(n0+lm)*ldb + lk;
  float acc[8][8];
#pragma unroll
  for (int i=0;i<8;++i)
#pragma unroll
    for (int j=0;j<8;++j) acc[i][j]=0.f;

  for (int kk=0; kk<K; kk+=8){
    float4 av = Arow ? *(const float4*)(Arow + kk) : make_float4(0.f,0.f,0.f,0.f);
    float4 bw = *(const float4*)(Brow + kk);
    __syncthreads();
    As[lk+0][lm]=av.x; As[lk+1][lm]=av.y; As[lk+2][lm]=av.z; As[lk+3][lm]=av.w;
    Bs[lk+0][lm]=bw.x; Bs[lk+1][lm]=bw.y; Bs[lk+2][lm]=bw.z; Bs[lk+3][lm]=bw.w;
    __syncthreads();
#pragma unroll
    for (int k=0;k<8;++k){
      float4 a0 = *(const float4*)&As[k][ty*8];
      float4 a1 = *(const float4*)&As[k][ty*8+4];
      float4 b0 = *(const float4*)&Bs[k][tx*4];
      float4 b1 = *(const float4*)&Bs[k][64+tx*4];
      float am[8]={a0.x,a0.y,a0.z,a0.w,a1.x,a1.y,a1.z,a1.w};
      float bm[8]={b0.x,b0.y,b0.z,b0.w,b1.x,b1.y,b1.z,b1.w};
#pragma unroll
      for (int i=0;i<8;++i)
#pragma unroll
        for (int j=0;j<8;++j) acc[i][j] += am[i]*bm[j];
    }
  }
  float4 bb0 = *(const float4*)&bias[n0+tx*4];
  float4 bb1 = *(const float4*)&bias[n0+64+tx*4];
#pragma unroll
  for (int i=0;i<8;++i){
    int r = r0 + ty*8 + i;
    float4 o0 = make_float4(acc[i][0]+bb0.x, acc[i][1]+bb0.y, acc[i][2]+bb0.z, acc[i][3]+bb0.w);
    float4 o1 = make_float4(acc[i][4]+bb1.x, acc[i][5]+bb1.y, acc[i][6]+bb1.z, acc[i][7]+bb1.w);
    *(float4*)(C + (size_t)r*ldc + n0 + tx*4)      = o0;
    *(float4*)(C + (size_t)r*ldc + n0 + 64 + tx*4) = o1;
  }
}

// ---------------- persistent encoder scan (cooperative) ----------------
// grid 256x256. Per step: P1 partial GEMM (2 dir x 16 ntile x 8 ksplit), P2 reduce+LSTM.
__global__ __launch_bounds__(256) void enc_scan(
    float* __restrict__ penc,
    const float* __restrict__ Gf, const float* __restrict__ Gb,
    const float* __restrict__ Whh_f, const float* __restrict__ Whh_b,
    float* __restrict__ h0f, float* __restrict__ h1f, float* __restrict__ cF,
    float* __restrict__ h0b, float* __restrict__ h1b, float* __restrict__ cB,
    float* __restrict__ encH, float* __restrict__ outR,
    const int* __restrict__ lens){
  cg::grid_group grid = cg::this_grid();
  __shared__ float As[8][64];
  __shared__ float Bs[8][128];
  const int tid = threadIdx.x;
  const int blk = blockIdx.x;
  const int dir = blk >> 7;
  const int sub = blk & 127;
  const int n0 = (sub & 15) * 128;
  const int k0 = (sub >> 4) * 64;
  const float* W = dir ? Whh_b : Whh_f;
  const int ty = tid>>5, tx = tid&31;
#pragma unroll 1
  for (int s=0; s<Sn; ++s){
    const float* hinF = (s&1) ? h1f : h0f;
    float* houtF      = (s&1) ? h0f : h1f;
    const float* hinB = (s&1) ? h1b : h0b;
    float* houtB      = (s&1) ? h0b : h1b;
    // ---- P1: partial GEMM h @ Whh^T (k-chunk of 64) ----
    {
      const float* h = dir ? hinB : hinF;
      float acc[8][4];
#pragma unroll
      for (int i=0;i<8;++i){ acc[i][0]=0.f;acc[i][1]=0.f;acc[i][2]=0.f;acc[i][3]=0.f; }
      for (int kk=0; kk<64; kk+=8){
        __syncthreads();
        if (tid < 128){
          int lm = tid>>1, lk = (tid&1)*4;
          float4 v = *(const float4*)(h + (size_t)lm*Hn + k0+kk+lk);
          As[lk+0][lm]=v.x; As[lk+1][lm]=v.y; As[lk+2][lm]=v.z; As[lk+3][lm]=v.w;
        } else {
          int t2 = tid-128;
          const float* wr = W + (size_t)(n0+t2)*Hn + k0+kk;
          float4 v0 = *(const float4*)(wr);
          float4 v1 = *(const float4*)(wr+4);
          Bs[0][t2]=v0.x; Bs[1][t2]=v0.y; Bs[2][t2]=v0.z; Bs[3][t2]=v0.w;
          Bs[4][t2]=v1.x; Bs[5][t2]=v1.y; Bs[6][t2]=v1.z; Bs[7][t2]=v1.w;
        }
        __syncthreads();
#pragma unroll
        for (int k=0;k<8;++k){
          float4 a0 = *(const float4*)&As[k][ty*8];
          float4 a1 = *(const float4*)&As[k][ty*8+4];
          float4 bv = *(const float4*)&Bs[k][tx*4];
          float am[8]={a0.x,a0.y,a0.z,a0.w,a1.x,a1.y,a1.z,a1.w};
          float bm[4]={bv.x,bv.y,bv.z,bv.w};
#pragma unroll
          for (int i=0;i<8;++i)
#pragma unroll
            for (int j=0;j<4;++j) acc[i][j] += am[i]*bm[j];
        }
      }
      float* out = penc + ((size_t)(dir*8 + (sub>>4))*64)*2048;
#pragma unroll
      for (int i=0;i<8;++i)
        *(float4*)(out + (size_t)(ty*8+i)*2048 + n0 + tx*4) =
            make_float4(acc[i][0],acc[i][1],acc[i][2],acc[i][3]);
    }
    __threadfence();
    grid.sync();
    // ---- P2: reduce + LSTM activation ----
    {
      int t = blk*256 + tid;             // 0..65535 = 2*64*512
      int u = t & 511, b = (t>>9) & 63, d2 = t>>15;
      const float* Gin = d2 ? Gb : Gf;
      const float* pe = penc + (size_t)d2*8*64*2048;
      float g[4];
#pragma unroll
      for (int gi=0; gi<4; ++gi){
        int n = gi*512 + u;
        float acc = Gin[((size_t)(b*Sn+s))*2048 + n];
#pragma unroll
        for (int ks=0; ks<8; ++ks) acc += pe[((size_t)ks*64 + b)*2048 + n];
        g[gi] = acc;
      }
      const float* hin = d2 ? hinB : hinF;
      float* hout = d2 ? houtB : houtF;
      float* c    = d2 ? cB : cF;
      int bu = b*512 + u;
      float ig=sigm(g[0]), fg=sigm(g[1]), gg=tanhf(g[2]), og=sigm(g[3]);
      float cp = c[bu];
      float cn = fg*cp + ig*gg;
      float hn = og*tanhf(cn);
      bool valid = s < lens[b];
      hout[bu] = valid ? hn : hin[bu];
      c[bu]    = valid ? cn : cp;
      if (d2==0) encH[((size_t)(b*Sn+s))*1024 + u] = valid ? hn : 0.f;
      else       outR[((size_t)(b*Sn+s))*512  + u] = valid ? hn : 0.f;
    }
    __threadfence();
    grid.sync();
  }
}

__global__ void reverse_bwd(const float* __restrict__ outR, const int* __restrict__ lens,
                            float* __restrict__ encH){
  int idx = blockIdx.x*blockDim.x+threadIdx.x;
  const int tot = Bn*Sn*(Hn/4);
  if (idx>=tot) return;
  int u4 = idx % (Hn/4);
  int bs = idx / (Hn/4);
  int s = bs % Sn, b = bs / Sn;
  int len = lens[b];
  float4 v = make_float4(0.f,0.f,0.f,0.f);
  if (s < len){
    int j = len-1-s;
    v = ((const float4*)(outR + ((size_t)(b*Sn+j))*Hn))[u4];
  }
  ((float4*)(encH + ((size_t)(b*Sn+s))*2*Hn + Hn))[u4] = v;
}

__global__ void proj_cat(const float* __restrict__ x1, const float* __restrict__ x2,
                         const float* __restrict__ W, const float* __restrict__ bias,
                         float* __restrict__ y){
  int tid = blockIdx.x*blockDim.x+threadIdx.x;   // Bn*Hn
  int u = tid % Hn, b = tid / Hn;
  float acc = bias[u];
  const float4* a1 = (const float4*)(x1 + (size_t)b*Hn);
  const float4* a2 = (const float4*)(x2 + (size_t)b*Hn);
  const float4* w  = (const float4*)(W + (size_t)u*2*Hn);
#pragma unroll 4
  for (int k=0;k<Hn/4;++k) acc += dot4(a1[k], w[k]);
#pragma unroll 4
  for (int k=0;k<Hn/4;++k) acc += dot4(a2[k], w[Hn/4+k]);
  y[tid]=acc;
}

// ---------------- persistent decoder scan (cooperative) ----------------
// grid 256x256. Per step: P1 gates partial (16 ntile x 16 ksplit),
// P2 per-batch {gate reduce + LSTM + attention + context} (64 blocks),
// P3 combine partial (8 ntile x 24 ksplit = 192 blocks), P4 combine reduce (128 blocks).
__global__ __launch_bounds__(256) void dec_scan(
    float* __restrict__ pdec, float* __restrict__ pcomb,
    const float* __restrict__ Gdy, const float* __restrict__ Whh_d,
    const float* __restrict__ Wih_d, const float* __restrict__ Wcomb,
    const float* __restrict__ bcomb,
    float* __restrict__ h0, float* __restrict__ h1, float* __restrict__ dC,
    const float* __restrict__ o0, float* __restrict__ outs,
    const float* __restrict__ eprj, const float* __restrict__ encH,
    float* __restrict__ actx, const int* __restrict__ lens){
  cg::grid_group grid = cg::this_grid();
  __shared__ float As[8][64];
  __shared__ float Bs[8][128];
  __shared__ float hs[512];
  __shared__ float es[Sn];
  __shared__ float sal[Sn];
  __shared__ float sinv_s;
  const int tid = threadIdx.x;
  const int blk = blockIdx.x;
#pragma unroll 1
  for (int t=0; t<Tn; ++t){
    const float* hprev = (t&1) ? h1 : h0;
    float* hcur        = (t&1) ? h0 : h1;
    const float* oprev = t ? (outs + (size_t)(t-1)*Bn*Hn) : o0;
    // ---- P1: gates partial [h|o] @ W^T, k-chunk of 64 ----
    {
      const int n0 = (blk&15)*128;
      const int k0 = (blk>>4)*64;
      const float* A2; int acol; const float* Bb; int ldb; int bcol;
      if (k0 < 512){ A2 = hprev; acol = k0;      Bb = Whh_d; ldb = Hn;    bcol = k0; }
      else         { A2 = oprev; acol = k0-512;  Bb = Wih_d; ldb = En+Hn; bcol = En + (k0-512); }
      const int ty = tid>>5, tx = tid&31;
      float acc[8][4];
#pragma unroll
      for (int i=0;i<8;++i){ acc[i][0]=0.f;acc[i][1]=0.f;acc[i][2]=0.f;acc[i][3]=0.f; }
      for (int kk=0; kk<64; kk+=8){
        __syncthreads();
        if (tid < 128){
          int lm = tid>>1, lk = (tid&1)*4;
          float4 v = *(const float4*)(A2 + (size_t)lm*Hn + acol+kk+lk);
          As[lk+0][lm]=v.x; As[lk+1][lm]=v.y; As[lk+2][lm]=v.z; As[lk+3][lm]=v.w;
        } else {
          int t2 = tid-128;
          const float* wr = Bb + (size_t)(n0+t2)*ldb + bcol+kk;
          float4 v0 = *(const float4*)(wr);
          float4 v1 = *(const float4*)(wr+4);
          Bs[0][t2]=v0.x; Bs[1][t2]=v0.y; Bs[2][t2]=v0.z; Bs[3][t2]=v0.w;
          Bs[4][t2]=v1.x; Bs[5][t2]=v1.y; Bs[6][t2]=v1.z; Bs[7][t2]=v1.w;
        }
        __syncthreads();
#pragma unroll
        for (int k=0;k<8;++k){
          float4 a0 = *(const float4*)&As[k][ty*8];
          float4 a1 = *(const float4*)&As[k][ty*8+4];
          float4 bv = *(const float4*)&Bs[k][tx*4];
          float am[8]={a0.x,a0.y,a0.z,a0.w,a1.x,a1.y,a1.z,a1.w};
          float bm[4]={bv.x,bv.y,bv.z,bv.w};
#pragma unroll
          for (int i=0;i<8;++i)
#pragma unroll
            for (int j=0;j<4;++j) acc[i][j] += am[i]*bm[j];
        }
      }
      float* out = pdec + (size_t)(blk>>4)*64*2048;
#pragma unroll
      for (int i=0;i<8;++i)
        *(float4*)(out + (size_t)(ty*8+i)*2048 + n0 + tx*4) =
            make_float4(acc[i][0],acc[i][1],acc[i][2],acc[i][3]);
    }
    __threadfence();
    grid.sync();
    // ---- P2: per-batch gate reduce + LSTM + attention + context ----
    if (blk < Bn){
      const int b = blk;
#pragma unroll
      for (int half=0; half<2; ++half){
        int u = tid + half*256;
        float g[4];
#pragma unroll
        for (int gi=0; gi<4; ++gi){
          int n = gi*512 + u;
          float acc = Gdy[((size_t)(t*Bn+b))*2048 + n];
#pragma unroll
          for (int ks=0; ks<16; ++ks) acc += pdec[((size_t)ks*64 + b)*2048 + n];
          g[gi]=acc;
        }
        float ig=sigm(g[0]), fg=sigm(g[1]), gg=tanhf(g[2]), og=sigm(g[3]);
        int bu = b*512+u;
        float cp = dC[bu];
        float cn = fg*cp + ig*gg;
        float hn = og*tanhf(cn);
        dC[bu]=cn;
        hcur[bu]=hn;
        hs[u]=hn;
      }
      __syncthreads();
      const int wv = tid>>6, lane = tid&63;
      const int len = lens[b];
      for (int si=0; si<10; ++si){
        int s = wv*10+si;
        const float* pr = eprj + ((size_t)(b*Sn+s))*Hn + lane*8;
        float4 p0 = *(const float4*)pr, p1 = *(const float4*)(pr+4);
        const float* hh = hs + lane*8;
        float4 hv0 = *(const float4*)hh, hv1 = *(const float4*)(hh+4);
        float acc = dot4(p0,hv0) + dot4(p1,hv1);
#pragma unroll
        for (int off=32; off; off>>=1) acc += __shfl_down(acc, off);
        if (lane==0) es[s] = (s>=1 && s<len) ? -INFINITY : acc;
      }
      __syncthreads();
      if (tid < 64){
        float e2 = (tid<Sn) ? es[tid] : -INFINITY;
        float m = e2;
#pragma unroll
        for (int off=32; off; off>>=1) m = fmaxf(m, __shfl_xor(m, off));
        float p = (tid<Sn) ? __expf(e2-m) : 0.f;
        float sum = p;
#pragma unroll
        for (int off=32; off; off>>=1) sum += __shfl_xor(sum, off);
        if (tid<Sn) sal[tid] = p;
        if (tid==0) sinv_s = 1.f/sum;
      }
      __syncthreads();
      float inv = sinv_s;
#pragma unroll
      for (int dq=0; dq<4; ++dq){
        int d = dq*256 + tid;
        float acc = 0.f;
        for (int s=0;s<Sn;++s) acc += sal[s]*encH[((size_t)(b*Sn+s))*1024 + d];
        actx[(size_t)b*1024 + d] = acc*inv;
      }
    }
    __threadfence();
    grid.sync();
    // ---- P3: combine partial [h|a] @ Wcomb^T ----
    if (blk < 192){
      const int n0 = (blk&7)*64;
      const int k0 = (blk>>3)*64;
      const float* A2; int lda2; int acol;
      if (k0 < 512){ A2 = hcur; lda2 = Hn;   acol = k0; }
      else         { A2 = actx; lda2 = 2*Hn; acol = k0-512; }
      const int ty = tid>>4, tx = tid&15;
      float acc[4][4];
#pragma unroll
      for (int i=0;i<4;++i){ acc[i][0]=0.f;acc[i][1]=0.f;acc[i][2]=0.f;acc[i][3]=0.f; }
      for (int kk=0; kk<64; kk+=8){
        __syncthreads();
        if (tid < 128){
          int lm = tid>>1, lk = (tid&1)*4;
          float4 v = *(const float4*)(A2 + (size_t)lm*lda2 + acol+kk+lk);
          As[lk+0][lm]=v.x; As[lk+1][lm]=v.y; As[lk+2][lm]=v.z; As[lk+3][lm]=v.w;
        } else {
          int t2 = tid-128;
          int lm = t2>>1, lk = (t2&1)*4;
          float4 v = *(const float4*)(Wcomb + (size_t)(n0+lm)*(3*Hn) + k0+kk+lk);
          Bs[lk+0][lm]=v.x; Bs[lk+1][lm]=v.y; Bs[lk+2][lm]=v.z; Bs[lk+3][lm]=v.w;
        }
        __syncthreads();
#pragma unroll
        for (int k=0;k<8;++k){
          float4 av = *(const float4*)&As[k][ty*4];
          float4 bv = *(const float4*)&Bs[k][tx*4];
          float am[4]={av.x,av.y,av.z,av.w};
          float bm[4]={bv.x,bv.y,bv.z,bv.w};
#pragma unroll
          for (int i=0;i<4;++i)
#pragma unroll
            for (int j=0;j<4;++j) acc[i][j] += am[i]*bm[j];
        }
      }
      float* out = pcomb + (size_t)(blk>>3)*64*512;
#pragma unroll
      for (int i=0;i<4;++i)
        *(float4*)(out + (size_t)(ty*4+i)*512 + n0 + tx*4) =
            make_float4(acc[i][0],acc[i][1],acc[i][2],acc[i][3]);
    }
    __threadfence();
    grid.sync();
    // ---- P4: combine reduce + tanh -> outs[t] ----
    if (blk < 128){
      int idx = blk*256 + tid;     // 0..32767
      int u = idx & 511, b2 = idx >> 9;
      float acc = bcomb[u];
#pragma unroll
      for (int kz=0; kz<24; ++kz) acc += pcomb[((size_t)kz*64 + b2)*512 + u];
      outs[(size_t)t*Bn*Hn + b2*512 + u] = tanhf(acc);
    }
    __threadfence();
    grid.sync();
  }
}

// f32 -> bf16 (RNE), 8 elements/thread
__global__ void cvt_bf16(const float* __restrict__ in, unsigned short* __restrict__ out, int n8){
  int i = blockIdx.x*blockDim.x + threadIdx.x;
  if (i>=n8) return;
  float4 a = ((const float4*)in)[i*2];
  float4 b = ((const float4*)in)[i*2+1];
  unsigned short r[8];
  r[0]=f2bf(a.x); r[1]=f2bf(a.y); r[2]=f2bf(a.z); r[3]=f2bf(a.w);
  r[4]=f2bf(b.x); r[5]=f2bf(b.y); r[6]=f2bf(b.z); r[7]=f2bf(b.w);
  ((uint4*)out)[i] = *(const uint4*)r;
}

// bf16 MFMA vocab projection with fused per-64-col (max,sumexp) stats.
// grid (250 vb, 20 rb), 256 threads = 4 waves (2x2 over 128x128 tile).
__global__ __launch_bounds__(256) void vocab_mfma(
    const unsigned short* __restrict__ A16, const unsigned short* __restrict__ W16,
    const float* __restrict__ bv, float* __restrict__ stats){
  __shared__ unsigned short Abf[128*64];
  __shared__ unsigned short Bbf[128*64];
  const int vb = blockIdx.x, rb = blockIdx.y;
  const int r0 = rb*128, v0 = vb*128;
  const int tid = threadIdx.x;
  const int w = tid>>6, lane = tid&63;
  const int wr = w>>1, wc = w&1;
  v4f acc[4][4];
#pragma unroll
  for (int i=0;i<4;++i)
#pragma unroll
    for (int j=0;j<4;++j) acc[i][j] = (v4f){0.f,0.f,0.f,0.f};
  const int srow = tid>>1;
  const int sk0  = (tid&1)*8;
  // fragment LDS offsets (XOR swizzle: elem_off k ^= ((row&7)<<3))
  const int arow = wr*64 + (lane&15);
  const int brow = wc*64 + (lane&15);
  const int kfrag = (lane>>4)*8;
  for (int ks=0; ks<8; ++ks){
    const int kb = ks*64;
    __syncthreads();
#pragma unroll
    for (int c=0;c<4;++c){
      int k = sk0 + c*16;
      int swz = k ^ ((srow&7)<<3);
      *(uint4*)&Abf[srow*64 + swz] = *(const uint4*)(A16 + (size_t)(r0+srow)*512 + kb + k);
      *(uint4*)&Bbf[srow*64 + swz] = *(const uint4*)(W16 + (size_t)(v0+srow)*512 + kb + k);
    }
    __syncthreads();
#pragma unroll
    for (int kk=0; kk<64; kk+=32){
      v8s af[4], bf[4];
#pragma unroll
      for (int mi=0;mi<4;++mi){
        int row = arow + mi*16;
        int k = kk + kfrag;
        af[mi] = *(const v8s*)&Abf[row*64 + (k ^ ((row&7)<<3))];
      }
#pragma unroll
      for (int ni=0;ni<4;++ni){
        int row = brow + ni*16;
        int k = kk + kfrag;
        bf[ni] = *(const v8s*)&Bbf[row*64 + (k ^ ((row&7)<<3))];
      }
#pragma unroll
      for (int mi=0;mi<4;++mi)
#pragma unroll
        for (int ni=0;ni<4;++ni)
          acc[mi][ni] = __builtin_amdgcn_mfma_f32_16x16x32_bf16(af[mi], bf[ni], acc[mi][ni], 0,0,0);
    }
  }
  // epilogue: bias + per-row (max, sumexp) over this wave's 64 cols
  float bj[4];
#pragma unroll
  for (int ni=0;ni<4;++ni) bj[ni] = bv[v0 + wc*64 + ni*16 + (lane&15)];
#pragma unroll
  for (int mi=0;mi<4;++mi){
#pragma unroll
    for (int r=0;r<4;++r){
      float x0 = acc[mi][0][r]+bj[0], x1 = acc[mi][1][r]+bj[1];
      float x2 = acc[mi][2][r]+bj[2], x3 = acc[mi][3][r]+bj[3];
      float mx = fmaxf(fmaxf(x0,x1), fmaxf(x2,x3));
#pragma unroll
      for (int off=1; off<16; off<<=1) mx = fmaxf(mx, __shfl_xor(mx, off));
      float se = __expf(x0-mx)+__expf(x1-mx)+__expf(x2-mx)+__expf(x3-mx);
#pragma unroll
      for (int off=1; off<16; off<<=1) se += __shfl_xor(se, off);
      if ((lane&15)==0){
        int row = r0 + wr*64 + mi*16 + (lane>>4)*4 + r;
        int chunk = vb*2 + wc;
        size_t o = ((size_t)row*NCH + chunk)*2;
        stats[o]   = mx;
        stats[o+1] = se;
      }
    }
  }
}

// wave-per-row LSE combine over 500 chunks
__global__ void row_lse(const float* __restrict__ stats, float* __restrict__ lse){
  int r = blockIdx.x*4 + (threadIdx.x>>6);
  int lane = threadIdx.x & 63;
  const float* st = stats + (size_t)r*NCH*2;
  float M = -INFINITY;
  for (int c=lane; c<NCH; c+=64) M = fmaxf(M, st[2*c]);
#pragma unroll
  for (int off=32; off; off>>=1) M = fmaxf(M, __shfl_xor(M, off));
  float S = 0.f;
  for (int c=lane; c<NCH; c+=64) S += __expf(st[2*c]-M)*st[2*c+1];
#pragma unroll
  for (int off=32; off; off>>=1) S += __shfl_xor(S, off);
  if (lane==0) lse[r] = M + logf(S);
}

__global__ void tgt_nll(const float* __restrict__ A, const float* __restrict__ Wv,
                        const float* __restrict__ bv, const int* __restrict__ tgt,
                        const float* __restrict__ lse, float* __restrict__ nll){
  int r = blockIdx.x;         // Rn blocks of 64
  int t = r / Bn, b = r % Bn;
  int v = tgt[b*Tn + t];
  int lane = threadIdx.x;
  const float* ar = A + (size_t)r*Hn;
  const float* wr = Wv + (size_t)v*Hn;
  float acc=0.f;
  for (int k=lane;k<Hn;k+=64) acc += ar[k]*wr[k];
#pragma unroll
  for (int off=32; off>0; off>>=1) acc += __shfl_down(acc, off);
  if (lane==0) nll[r] = lse[r] - (acc + bv[v]);
}

__global__ void final_mean(const float* __restrict__ nll, float* __restrict__ out){
  __shared__ float red[256];
  float acc=0.f;
  for (int i=threadIdx.x;i<Rn;i+=256) acc += nll[i];
  red[threadIdx.x]=acc;
  __syncthreads();
  for (int off=128; off>0; off>>=1){
    if (threadIdx.x<off) red[threadIdx.x]+=red[threadIdx.x+off];
    __syncthreads();
  }
  if (threadIdx.x==0) out[0] = red[0] / (float)Rn;
}

extern "C" void kernel_launch(void* const* d_in, const int* in_sizes, int n_in,
                              void* d_out, int out_size, void* d_ws, size_t ws_size,
                              hipStream_t stream){
  (void)in_sizes; (void)n_in; (void)out_size; (void)ws_size;
  const int*   srcP  = (const int*)  d_in[0];
  const int*   tgtP  = (const int*)  d_in[1];
  const int*   lens  = (const int*)  d_in[2];
  const float* semb  = (const float*)d_in[3];
  const float* temb  = (const float*)d_in[4];
  const float* Wih_f = (const float*)d_in[5];
  const float* Whh_f = (const float*)d_in[6];
  const float* b_f   = (const float*)d_in[7];
  const float* Wih_b = (const float*)d_in[8];
  const float* Whh_b = (const float*)d_in[9];
  const float* b_b   = (const float*)d_in[10];
  const float* Wih_d = (const float*)d_in[11];
  const float* Whh_d = (const float*)d_in[12];
  const float* b_d   = (const float*)d_in[13];
  const float* Whp   = (const float*)d_in[14];
  const float* bhp   = (const float*)d_in[15];
  const float* Wcp   = (const float*)d_in[16];
  const float* bcp   = (const float*)d_in[17];
  const float* Watt  = (const float*)d_in[18];
  const float* batt  = (const float*)d_in[19];
  const float* Wcomb = (const float*)d_in[20];
  const float* bcomb = (const float*)d_in[21];
  const float* Wvoc  = (const float*)d_in[22];
  const float* bvoc  = (const float*)d_in[23];

  float* w = (float*)d_ws;
  size_t off=0;
  auto alloc=[&](size_t n){ float* p = w+off; off+=n; return p; };
  const size_t BH = (size_t)Bn*Hn;
  float* encH = alloc((size_t)Bn*Sn*2*Hn);
  float* outR = alloc((size_t)Bn*Sn*Hn);
  float* eprj = alloc((size_t)Bn*Sn*Hn);
  float* outs = alloc((size_t)Tn*Bn*Hn);
  float* Gf   = alloc((size_t)Bn*Sn*4*Hn);
  float* Gb   = alloc((size_t)Bn*Sn*4*Hn);
  float* Gdy  = alloc((size_t)Tn*Bn*4*Hn);
  float* penc = alloc((size_t)2*8*64*2048);
  float* pdec = alloc((size_t)16*64*2048);
  float* pcomb= alloc((size_t)24*64*512);
  float* small= alloc(10*BH);
  float* actx = alloc((size_t)Bn*2*Hn);
  float* lse  = alloc(Rn);
  float* nll  = alloc(Rn);
  int* grev = (int*)alloc(Bn*Sn);
  int* gtgt = (int*)alloc(Tn*Bn);
  // aliases (lifetime-disjoint):
  unsigned short* W16 = (unsigned short*)Gf;     // 16.4M ush over Gf+Gb (dead after enc_scan)
  unsigned short* A16 = (unsigned short*)pcomb;  // 1.31M ush over pcomb (dead after dec_scan)
  float* stats = penc;                           // 2.56M f over penc+pdec (dead after scans)

  float* hF0 = small + 0*BH; float* hF1 = small + 1*BH; float* cF = small + 2*BH;
  float* hB0 = small + 3*BH; float* hB1 = small + 4*BH; float* cB = small + 5*BH;
  float* dH0 = small + 6*BH; float* dH1 = small + 7*BH; float* dC = small + 8*BH;
  float* o0  = small + 9*BH;

  {
    int n4 = (int)(10*BH/4);
    zero_f4<<<(n4+255)/256, 256, 0, stream>>>((float4*)small, n4);
  }
  build_maps<<<(Bn*Sn+255)/256, 256, 0, stream>>>(srcP, tgtP, lens, grev, gtgt);

  // input-side gate precompute
  gemm128<<<dim3(16,20), 256, 0, stream>>>(semb, En, srcP, Wih_f, En, b_f, Gf, 4*Hn, En);
  gemm128<<<dim3(16,20), 256, 0, stream>>>(semb, En, grev, Wih_b, En, b_b, Gb, 4*Hn, En);
  gemm128<<<dim3(16,20), 256, 0, stream>>>(temb, En, gtgt, Wih_d, En+Hn, b_d, Gdy, 4*Hn, En);

  // encoder scan (persistent cooperative kernel)
  {
    void* p_penc=(void*)penc; void* p_Gf=(void*)Gf; void* p_Gb=(void*)Gb;
    void* p_Wf=(void*)Whh_f; void* p_Wb=(void*)Whh_b;
    void* p_h0f=(void*)hF0; void* p_h1f=(void*)hF1; void* p_cF=(void*)cF;
    void* p_h0b=(void*)hB0; void* p_h1b=(void*)hB1; void* p_cB=(void*)cB;
    void* p_encH=(void*)encH; void* p_outR=(void*)outR; void* p_lens=(void*)lens;
    void* args[] = {&p_penc,&p_Gf,&p_Gb,&p_Wf,&p_Wb,&p_h0f,&p_h1f,&p_cF,
                    &p_h0b,&p_h1b,&p_cB,&p_encH,&p_outR,&p_lens};
    hipLaunchCooperativeKernel((const void*)enc_scan, dim3(256), dim3(256), args, 0, stream);
  }
  // Wvoc -> bf16 (over dead Gf/Gb region)
  cvt_bf16<<<(VTn*Hn/8 + 255)/256, 256, 0, stream>>>(Wvoc, W16, VTn*Hn/8);

  {
    int tot = Bn*Sn*(Hn/4);
    reverse_bwd<<<(tot+255)/256, 256, 0, stream>>>(outR, lens, encH);
  }
  proj_cat<<<(Bn*Hn)/256, 256, 0, stream>>>(hF0, hB0, Whp, bhp, dH0);
  proj_cat<<<(Bn*Hn)/256, 256, 0, stream>>>(cF,  cB,  Wcp, bcp, dC);
  gemm128<<<dim3(4,20), 256, 0, stream>>>(encH, 2*Hn, nullptr, Watt, 2*Hn, batt, eprj, Hn, 2*Hn);

  // decoder scan (persistent cooperative kernel)
  {
    void* p_pdec=(void*)pdec; void* p_pcomb=(void*)pcomb; void* p_Gdy=(void*)Gdy;
    void* p_Whh=(void*)Whh_d; void* p_Wih=(void*)Wih_d; void* p_Wc=(void*)Wcomb;
    void* p_bc=(void*)bcomb; void* p_h0=(void*)dH0; void* p_h1=(void*)dH1;
    void* p_dC=(void*)dC; void* p_o0=(void*)o0; void* p_outs=(void*)outs;
    void* p_eprj=(void*)eprj; void* p_encH=(void*)encH; void* p_actx=(void*)actx;
    void* p_lens=(void*)lens;
    void* args[] = {&p_pdec,&p_pcomb,&p_Gdy,&p_Whh,&p_Wih,&p_Wc,&p_bc,
                    &p_h0,&p_h1,&p_dC,&p_o0,&p_outs,&p_eprj,&p_encH,&p_actx,&p_lens};
    hipLaunchCooperativeKernel((const void*)dec_scan, dim3(256), dim3(256), args, 0, stream);
  }

  // vocab pipeline (bf16 MFMA)
  cvt_bf16<<<(Rn*Hn/8 + 255)/256, 256, 0, stream>>>(outs, A16, Rn*Hn/8);
  vocab_mfma<<<dim3(VTn/128, Rn/128), 256, 0, stream>>>(A16, W16, bvoc, stats);
  row_lse<<<Rn/4, 256, 0, stream>>>(stats, lse);
  tgt_nll<<<Rn, 64, 0, stream>>>(outs, Wvoc, bvoc, tgtP, lse, nll);
  final_mean<<<1, 256, 0, stream>>>(nll, (float*)d_out);
}

// Round 4
// 2754.187 us; speedup vs baseline: 6.2768x; 6.2768x over previous
//
#include <hip/hip_runtime.h>
#include <math.h>

#define En 256
#define Hn 512
#define Bn 64
#define Sn 40
#define Tn 40
#define VTn 32000
#define Rn (Tn*Bn)
#define NCH 500   // 32000 / 64 stat chunks

typedef short v8s __attribute__((ext_vector_type(8)));
typedef float v4f __attribute__((ext_vector_type(4)));

__device__ __forceinline__ float dot4(float4 a, float4 b){
  return a.x*b.x + a.y*b.y + a.z*b.z + a.w*b.w;
}
__device__ __forceinline__ float sigm(float x){ return 1.f/(1.f+__expf(-x)); }
__device__ __forceinline__ unsigned short f2bf(float f){
  unsigned u = __float_as_uint(f);
  unsigned r = u + 0x7FFFu + ((u>>16)&1u);
  return (unsigned short)(r>>16);
}

__global__ void zero_f4(float4* p, int n4){
  int i = blockIdx.x*blockDim.x+threadIdx.x;
  if (i<n4) p[i]=make_float4(0.f,0.f,0.f,0.f);
}

__global__ void build_maps(const int* __restrict__ src, const int* __restrict__ tgt,
                           const int* __restrict__ lens, int* __restrict__ grev,
                           int* __restrict__ gtgt){
  int r = blockIdx.x*blockDim.x+threadIdx.x;
  if (r >= Bn*Sn) return;
  int b = r / Sn, s = r % Sn;
  int j = lens[b]-1-s;
  grev[r] = (j>=0) ? src[b*Sn+j] : -1;
  int t2 = r >> 6, b2 = r & 63;   // Rn == Bn*Sn == 2560
  gtgt[r] = tgt[b2*Tn + t2];
}

// C[M,N] = gatherRows(A)[M,lda] @ B[N,ldb]^T + bias ; 128x128 tiles, BK=8
__global__ __launch_bounds__(256) void gemm128(const float* __restrict__ A, int lda,
                                               const int* __restrict__ gather,
                                               const float* __restrict__ B, int ldb,
                                               const float* __restrict__ bias,
                                               float* __restrict__ C, int ldc, int K){
  __shared__ float As[8][128];
  __shared__ float Bs[8][128];
  const int n0 = blockIdx.x*128, r0 = blockIdx.y*128;
  const int tid = threadIdx.x;
  const int tx = tid & 15, ty = tid >> 4;
  const int lm = tid >> 1, lk = (tid & 1)*4;
  int ar = gather ? gather[r0+lm] : (r0+lm);
  const float* Arow = (ar>=0) ? (A + (size_t)ar*lda + lk) : nullptr;
  const float* Brow = B + (size_t)(n0+lm)*ldb + lk;
  float acc[8][8];
#pragma unroll
  for (int i=0;i<8;++i)
#pragma unroll
    for (int j=0;j<8;++j) acc[i][j]=0.f;

  for (int kk=0; kk<K; kk+=8){
    float4 av = Arow ? *(const float4*)(Arow + kk) : make_float4(0.f,0.f,0.f,0.f);
    float4 bw = *(const float4*)(Brow + kk);
    __syncthreads();
    As[lk+0][lm]=av.x; As[lk+1][lm]=av.y; As[lk+2][lm]=av.z; As[lk+3][lm]=av.w;
    Bs[lk+0][lm]=bw.x; Bs[lk+1][lm]=bw.y; Bs[lk+2][lm]=bw.z; Bs[lk+3][lm]=bw.w;
    __syncthreads();
#pragma unroll
    for (int k=0;k<8;++k){
      float4 a0 = *(const float4*)&As[k][ty*8];
      float4 a1 = *(const float4*)&As[k][ty*8+4];
      float4 b0 = *(const float4*)&Bs[k][tx*4];
      float4 b1 = *(const float4*)&Bs[k][64+tx*4];
      float am[8]={a0.x,a0.y,a0.z,a0.w,a1.x,a1.y,a1.z,a1.w};
      float bm[8]={b0.x,b0.y,b0.z,b0.w,b1.x,b1.y,b1.z,b1.w};
#pragma unroll
      for (int i=0;i<8;++i)
#pragma unroll
        for (int j=0;j<8;++j) acc[i][j] += am[i]*bm[j];
    }
  }
  float4 bb0 = *(const float4*)&bias[n0+tx*4];
  float4 bb1 = *(const float4*)&bias[n0+64+tx*4];
#pragma unroll
  for (int i=0;i<8;++i){
    int r = r0 + ty*8 + i;
    float4 o0 = make_float4(acc[i][0]+bb0.x, acc[i][1]+bb0.y, acc[i][2]+bb0.z, acc[i][3]+bb0.w);
    float4 o1 = make_float4(acc[i][4]+bb1.x, acc[i][5]+bb1.y, acc[i][6]+bb1.z, acc[i][7]+bb1.w);
    *(float4*)(C + (size_t)r*ldc + n0 + tx*4)      = o0;
    *(float4*)(C + (size_t)r*ldc + n0 + 64 + tx*4) = o1;
  }
}

// Encoder recurrent partial GEMM. grid (16 ntile, 8 ksplit, 2 dir), block 256
__global__ __launch_bounds__(256) void enc_partial(const float* __restrict__ hf,
                                                   const float* __restrict__ hb,
                                                   const float* __restrict__ Wf,
                                                   const float* __restrict__ Wb,
                                                   float* __restrict__ penc){
  const int dir = blockIdx.z;
  const float* h = dir ? hb : hf;
  const float* W = dir ? Wb : Wf;
  const int n0 = blockIdx.x*128;
  const int k0 = blockIdx.y*64;
  __shared__ float As[8][64];
  __shared__ float Bs[8][128];
  const int tid = threadIdx.x;
  const int ty = tid>>5, tx = tid&31;
  float acc[8][4];
#pragma unroll
  for (int i=0;i<8;++i){ acc[i][0]=0.f;acc[i][1]=0.f;acc[i][2]=0.f;acc[i][3]=0.f; }
  for (int kk=0; kk<64; kk+=8){
    __syncthreads();
    if (tid < 128){
      int lm = tid>>1, lk = (tid&1)*4;
      float4 v = *(const float4*)(h + (size_t)lm*Hn + k0+kk+lk);
      As[lk+0][lm]=v.x; As[lk+1][lm]=v.y; As[lk+2][lm]=v.z; As[lk+3][lm]=v.w;
    } else {
      int t2 = tid-128;
      const float* wr = W + (size_t)(n0+t2)*Hn + k0+kk;
      float4 v0 = *(const float4*)(wr);
      float4 v1 = *(const float4*)(wr+4);
      Bs[0][t2]=v0.x; Bs[1][t2]=v0.y; Bs[2][t2]=v0.z; Bs[3][t2]=v0.w;
      Bs[4][t2]=v1.x; Bs[5][t2]=v1.y; Bs[6][t2]=v1.z; Bs[7][t2]=v1.w;
    }
    __syncthreads();
#pragma unroll
    for (int k=0;k<8;++k){
      float4 a0 = *(const float4*)&As[k][ty*8];
      float4 a1 = *(const float4*)&As[k][ty*8+4];
      float4 bv = *(const float4*)&Bs[k][tx*4];
      float am[8]={a0.x,a0.y,a0.z,a0.w,a1.x,a1.y,a1.z,a1.w};
      float bm[4]={bv.x,bv.y,bv.z,bv.w};
#pragma unroll
      for (int i=0;i<8;++i)
#pragma unroll
        for (int j=0;j<4;++j) acc[i][j] += am[i]*bm[j];
    }
  }
  float* out = penc + ((size_t)(dir*8 + blockIdx.y)*64)*2048;
#pragma unroll
  for (int i=0;i<8;++i)
    *(float4*)(out + (size_t)(ty*8+i)*2048 + n0 + tx*4) =
        make_float4(acc[i][0],acc[i][1],acc[i][2],acc[i][3]);
}

// Encoder reduce + LSTM activation, both dirs. grid 256 x 256.
__global__ void enc_reduce(const float* __restrict__ penc,
                           const float* __restrict__ Gf, const float* __restrict__ Gb,
                           const float* __restrict__ hin_f, float* __restrict__ hout_f,
                           float* __restrict__ c_f,
                           const float* __restrict__ hin_b, float* __restrict__ hout_b,
                           float* __restrict__ c_b,
                           float* __restrict__ encH, float* __restrict__ outR,
                           const int* __restrict__ lens, int s){
  int t = blockIdx.x*blockDim.x + threadIdx.x;   // 2*64*512
  int u = t & 511, b = (t>>9) & 63, dir = t>>15;
  const float* Gin = dir ? Gb : Gf;
  const float* pe = penc + (size_t)dir*8*64*2048;
  float g[4];
#pragma unroll
  for (int gi=0; gi<4; ++gi){
    int n = gi*512 + u;
    float acc = Gin[((size_t)(b*Sn+s))*2048 + n];
#pragma unroll
    for (int ks=0; ks<8; ++ks) acc += pe[((size_t)ks*64 + b)*2048 + n];
    g[gi] = acc;
  }
  const float* hin = dir ? hin_b : hin_f;
  float* hout = dir ? hout_b : hout_f;
  float* c    = dir ? c_b : c_f;
  int bu = b*512 + u;
  float ig=sigm(g[0]), fg=sigm(g[1]), gg=tanhf(g[2]), og=sigm(g[3]);
  float cp = c[bu];
  float cn = fg*cp + ig*gg;
  float hn = og*tanhf(cn);
  bool valid = s < lens[b];
  hout[bu] = valid ? hn : hin[bu];
  c[bu]    = valid ? cn : cp;
  if (dir==0) encH[((size_t)(b*Sn+s))*1024 + u] = valid ? hn : 0.f;
  else        outR[((size_t)(b*Sn+s))*512  + u] = valid ? hn : 0.f;
}

__global__ void reverse_bwd(const float* __restrict__ outR, const int* __restrict__ lens,
                            float* __restrict__ encH){
  int idx = blockIdx.x*blockDim.x+threadIdx.x;
  const int tot = Bn*Sn*(Hn/4);
  if (idx>=tot) return;
  int u4 = idx % (Hn/4);
  int bs = idx / (Hn/4);
  int s = bs % Sn, b = bs / Sn;
  int len = lens[b];
  float4 v = make_float4(0.f,0.f,0.f,0.f);
  if (s < len){
    int j = len-1-s;
    v = ((const float4*)(outR + ((size_t)(b*Sn+j))*Hn))[u4];
  }
  ((float4*)(encH + ((size_t)(b*Sn+s))*2*Hn + Hn))[u4] = v;
}

__global__ void proj_cat(const float* __restrict__ x1, const float* __restrict__ x2,
                         const float* __restrict__ W, const float* __restrict__ bias,
                         float* __restrict__ y){
  int tid = blockIdx.x*blockDim.x+threadIdx.x;   // Bn*Hn
  int u = tid % Hn, b = tid / Hn;
  float acc = bias[u];
  const float4* a1 = (const float4*)(x1 + (size_t)b*Hn);
  const float4* a2 = (const float4*)(x2 + (size_t)b*Hn);
  const float4* w  = (const float4*)(W + (size_t)u*2*Hn);
#pragma unroll 4
  for (int k=0;k<Hn/4;++k) acc += dot4(a1[k], w[k]);
#pragma unroll 4
  for (int k=0;k<Hn/4;++k) acc += dot4(a2[k], w[Hn/4+k]);
  y[tid]=acc;
}

// -------- Decoder K1: gates partial + (o-reconstruction from pcomb) + outs writer --------
// grid 384 x 256. blocks 0..255: partial GEMM k-chunk of 64 (k=1024 = [h|o]).
//   k>=512 blocks reconstruct the o-slice from pcomb (24-way reduce + tanh) in LDS.
// blocks 256..383: materialize outs[t-1] (f32 + bf16) from pcomb. (idle at t==0)
__global__ __launch_bounds__(256) void dec_gates(
    const float* __restrict__ hprev, const float* __restrict__ Whh_d,
    const float* __restrict__ Wih_d, const float* __restrict__ pcomb,
    const float* __restrict__ bcomb, float* __restrict__ pdec,
    float* __restrict__ outs, unsigned short* __restrict__ A16, int t){
  const int blk = blockIdx.x;
  const int tid = threadIdx.x;
  if (blk >= 256){
    if (t == 0) return;
    int idx = (blk-256)*256 + tid;     // 0..32767 = 64*512
    int u = idx & 511, b = idx >> 9;
    float acc = bcomb[u];
#pragma unroll 8
    for (int kz=0; kz<24; ++kz) acc += pcomb[((size_t)(kz*64+b))*512 + u];
    float o = tanhf(acc);
    size_t r = (size_t)(t-1)*Bn + b;
    outs[r*512 + u] = o;
    A16[r*512 + u] = f2bf(o);
    return;
  }
  const int n0 = (blk & 15) * 128;
  const int k0 = (blk >> 4) * 64;
  const int ty = tid>>5, tx = tid&31;
  float* out = pdec + (size_t)(blk>>4)*64*2048;
  const bool opath = (k0 >= 512);
  if (opath && t == 0){   // o_prev = 0 -> zero partials
#pragma unroll
    for (int i=0;i<8;++i)
      *(float4*)(out + (size_t)(ty*8+i)*2048 + n0 + tx*4) = make_float4(0.f,0.f,0.f,0.f);
    return;
  }
  __shared__ float As[8][64];
  __shared__ float Bs[8][128];
  __shared__ float ot[64][68];   // [d_local][b], padded for bank safety
  const float* Bb; int ldb; int bcol;
  if (!opath){ Bb = Whh_d; ldb = Hn;    bcol = k0; }
  else       { Bb = Wih_d; ldb = En+Hn; bcol = En + (k0-512); }
  if (opath){
    const int d0 = k0 - 512;
    for (int idx = tid; idx < 64*16; idx += 256){
      int dq = idx & 15, b = idx >> 4;
      float4 a4 = *(const float4*)&bcomb[d0 + dq*4];
#pragma unroll 8
      for (int kz=0; kz<24; ++kz){
        float4 p = *(const float4*)&pcomb[((size_t)(kz*64+b))*512 + d0 + dq*4];
        a4.x+=p.x; a4.y+=p.y; a4.z+=p.z; a4.w+=p.w;
      }
      ot[dq*4+0][b]=tanhf(a4.x);
      ot[dq*4+1][b]=tanhf(a4.y);
      ot[dq*4+2][b]=tanhf(a4.z);
      ot[dq*4+3][b]=tanhf(a4.w);
    }
  }
  float acc[8][4];
#pragma unroll
  for (int i=0;i<8;++i){ acc[i][0]=0.f;acc[i][1]=0.f;acc[i][2]=0.f;acc[i][3]=0.f; }
  for (int kk=0; kk<64; kk+=8){
    __syncthreads();
    if (!opath && tid < 128){
      int lm = tid>>1, lk = (tid&1)*4;
      float4 v = *(const float4*)(hprev + (size_t)lm*Hn + k0+kk+lk);
      As[lk+0][lm]=v.x; As[lk+1][lm]=v.y; As[lk+2][lm]=v.z; As[lk+3][lm]=v.w;
    }
    if (tid >= 128){
      int t2 = tid-128;
      const float* wr = Bb + (size_t)(n0+t2)*ldb + bcol+kk;
      float4 v0 = *(const float4*)(wr);
      float4 v1 = *(const float4*)(wr+4);
      Bs[0][t2]=v0.x; Bs[1][t2]=v0.y; Bs[2][t2]=v0.z; Bs[3][t2]=v0.w;
      Bs[4][t2]=v1.x; Bs[5][t2]=v1.y; Bs[6][t2]=v1.z; Bs[7][t2]=v1.w;
    }
    __syncthreads();
    if (opath){
#pragma unroll
      for (int k=0;k<8;++k){
        float4 bv = *(const float4*)&Bs[k][tx*4];
        float bm[4]={bv.x,bv.y,bv.z,bv.w};
        float am[8];
#pragma unroll
        for (int i=0;i<8;++i) am[i] = ot[kk+k][ty*8+i];
#pragma unroll
        for (int i=0;i<8;++i)
#pragma unroll
          for (int j=0;j<4;++j) acc[i][j] += am[i]*bm[j];
      }
    } else {
#pragma unroll
      for (int k=0;k<8;++k){
        float4 a0 = *(const float4*)&As[k][ty*8];
        float4 a1 = *(const float4*)&As[k][ty*8+4];
        float4 bv = *(const float4*)&Bs[k][tx*4];
        float am[8]={a0.x,a0.y,a0.z,a0.w,a1.x,a1.y,a1.z,a1.w};
        float bm[4]={bv.x,bv.y,bv.z,bv.w};
#pragma unroll
        for (int i=0;i<8;++i)
#pragma unroll
          for (int j=0;j<4;++j) acc[i][j] += am[i]*bm[j];
      }
    }
  }
#pragma unroll
  for (int i=0;i<8;++i)
    *(float4*)(out + (size_t)(ty*8+i)*2048 + n0 + tx*4) =
        make_float4(acc[i][0],acc[i][1],acc[i][2],acc[i][3]);
}

// -------- Decoder K2: per-batch gate reduce + LSTM + attention + context. grid 64x256 --------
__global__ __launch_bounds__(256) void dec_fused(
    const float* __restrict__ pdec, const float* __restrict__ Gdy,
    float* __restrict__ hcur, float* __restrict__ dC,
    const float* __restrict__ eprj, const float* __restrict__ encH,
    float* __restrict__ actx, const int* __restrict__ lens, int t){
  const int b = blockIdx.x;
  const int tid = threadIdx.x;
  __shared__ float hs[512];
  __shared__ float es[Sn];
  __shared__ float sal[Sn];
  __shared__ float sinv_s;
#pragma unroll
  for (int half=0; half<2; ++half){
    int u = tid + half*256;
    float g[4];
#pragma unroll
    for (int gi=0; gi<4; ++gi){
      int n = gi*512 + u;
      float acc = Gdy[((size_t)(t*Bn+b))*2048 + n];
#pragma unroll
      for (int ks=0; ks<16; ++ks) acc += pdec[((size_t)ks*64 + b)*2048 + n];
      g[gi]=acc;
    }
    float ig=sigm(g[0]), fg=sigm(g[1]), gg=tanhf(g[2]), og=sigm(g[3]);
    int bu = b*512+u;
    float cp = dC[bu];
    float cn = fg*cp + ig*gg;
    float hn = og*tanhf(cn);
    dC[bu]=cn;
    hcur[bu]=hn;
    hs[u]=hn;
  }
  __syncthreads();
  const int wv = tid>>6, lane = tid&63;
  const int len = lens[b];
  for (int si=0; si<10; ++si){
    int s = wv*10+si;
    const float* pr = eprj + ((size_t)(b*Sn+s))*Hn + lane*8;
    float4 p0 = *(const float4*)pr, p1 = *(const float4*)(pr+4);
    const float* hh = hs + lane*8;
    float4 hv0 = *(const float4*)hh, hv1 = *(const float4*)(hh+4);
    float acc = dot4(p0,hv0) + dot4(p1,hv1);
#pragma unroll
    for (int off=32; off; off>>=1) acc += __shfl_down(acc, off);
    if (lane==0) es[s] = (s>=1 && s<len) ? -INFINITY : acc;
  }
  __syncthreads();
  if (tid < 64){
    float e2 = (tid<Sn) ? es[tid] : -INFINITY;
    float m = e2;
#pragma unroll
    for (int off=32; off; off>>=1) m = fmaxf(m, __shfl_xor(m, off));
    float p = (tid<Sn) ? __expf(e2-m) : 0.f;
    float sum = p;
#pragma unroll
    for (int off=32; off; off>>=1) sum += __shfl_xor(sum, off);
    if (tid<Sn) sal[tid] = p;
    if (tid==0) sinv_s = 1.f/sum;
  }
  __syncthreads();
  float inv = sinv_s;
#pragma unroll
  for (int dq=0; dq<4; ++dq){
    int d = dq*256 + tid;
    float acc = 0.f;
    for (int s=0;s<Sn;++s) acc += sal[s]*encH[((size_t)(b*Sn+s))*1024 + d];
    actx[(size_t)b*1024 + d] = acc*inv;
  }
}

// Combine partial: [h|a] @ Wcomb^T ; grid (8 ntile of 64, 24 ksplit of 64)
__global__ __launch_bounds__(256) void comb_partial(const float* __restrict__ hcur,
                                                    const float* __restrict__ actx,
                                                    const float* __restrict__ Wcomb,
                                                    float* __restrict__ pcomb){
  const int n0 = blockIdx.x*64;
  const int k0 = blockIdx.y*64;
  const float* A; int lda; int acol;
  if (k0 < 512){ A = hcur; lda = Hn;   acol = k0; }
  else         { A = actx; lda = 2*Hn; acol = k0-512; }
  __shared__ float As[8][64];
  __shared__ float Bs[8][64];
  const int tid = threadIdx.x;
  const int ty = tid>>4, tx = tid&15;
  float acc[4][4];
#pragma unroll
  for (int i=0;i<4;++i){ acc[i][0]=0.f;acc[i][1]=0.f;acc[i][2]=0.f;acc[i][3]=0.f; }
  for (int kk=0; kk<64; kk+=8){
    __syncthreads();
    if (tid < 128){
      int lm = tid>>1, lk = (tid&1)*4;
      float4 v = *(const float4*)(A + (size_t)lm*lda + acol+kk+lk);
      As[lk+0][lm]=v.x; As[lk+1][lm]=v.y; As[lk+2][lm]=v.z; As[lk+3][lm]=v.w;
    } else {
      int t2 = tid-128;
      int lm = t2>>1, lk = (t2&1)*4;
      float4 v = *(const float4*)(Wcomb + (size_t)(n0+lm)*(3*Hn) + k0+kk+lk);
      Bs[lk+0][lm]=v.x; Bs[lk+1][lm]=v.y; Bs[lk+2][lm]=v.z; Bs[lk+3][lm]=v.w;
    }
    __syncthreads();
#pragma unroll
    for (int k=0;k<8;++k){
      float4 av = *(const float4*)&As[k][ty*4];
      float4 bv = *(const float4*)&Bs[k][tx*4];
      float am[4]={av.x,av.y,av.z,av.w};
      float bm[4]={bv.x,bv.y,bv.z,bv.w};
#pragma unroll
      for (int i=0;i<4;++i)
#pragma unroll
        for (int j=0;j<4;++j) acc[i][j] += am[i]*bm[j];
    }
  }
  float* out = pcomb + (size_t)blockIdx.y*64*512;
#pragma unroll
  for (int i=0;i<4;++i)
    *(float4*)(out + (size_t)(ty*4+i)*512 + n0 + tx*4) =
        make_float4(acc[i][0],acc[i][1],acc[i][2],acc[i][3]);
}

// Last step's combine reduce (outs[Tn-1] f32 + bf16). grid 128 x 256.
__global__ void comb_last(const float* __restrict__ pcomb, const float* __restrict__ bcomb,
                          float* __restrict__ outs, unsigned short* __restrict__ A16){
  int idx = blockIdx.x*256 + threadIdx.x;     // 0..32767
  int u = idx & 511, b = idx >> 9;
  float acc = bcomb[u];
#pragma unroll 8
  for (int kz=0; kz<24; ++kz) acc += pcomb[((size_t)(kz*64+b))*512 + u];
  float o = tanhf(acc);
  size_t r = (size_t)(Tn-1)*Bn + b;
  outs[r*512 + u] = o;
  A16[r*512 + u] = f2bf(o);
}

// f32 -> bf16 (RNE), 8 elements/thread
__global__ void cvt_bf16(const float* __restrict__ in, unsigned short* __restrict__ out, int n8){
  int i = blockIdx.x*blockDim.x + threadIdx.x;
  if (i>=n8) return;
  float4 a = ((const float4*)in)[i*2];
  float4 b = ((const float4*)in)[i*2+1];
  unsigned short r[8];
  r[0]=f2bf(a.x); r[1]=f2bf(a.y); r[2]=f2bf(a.z); r[3]=f2bf(a.w);
  r[4]=f2bf(b.x); r[5]=f2bf(b.y); r[6]=f2bf(b.z); r[7]=f2bf(b.w);
  ((uint4*)out)[i] = *(const uint4*)r;
}

// bf16 MFMA vocab projection with fused per-64-col (max,sumexp) stats.
// grid (250 vb, 20 rb), 256 threads = 4 waves (2x2 over 128x128 tile).
__global__ __launch_bounds__(256) void vocab_mfma(
    const unsigned short* __restrict__ A16, const unsigned short* __restrict__ W16,
    const float* __restrict__ bv, float* __restrict__ stats){
  __shared__ unsigned short Abf[128*64];
  __shared__ unsigned short Bbf[128*64];
  const int vb = blockIdx.x, rb = blockIdx.y;
  const int r0 = rb*128, v0 = vb*128;
  const int tid = threadIdx.x;
  const int w = tid>>6, lane = tid&63;
  const int wr = w>>1, wc = w&1;
  v4f acc[4][4];
#pragma unroll
  for (int i=0;i<4;++i)
#pragma unroll
    for (int j=0;j<4;++j) acc[i][j] = (v4f){0.f,0.f,0.f,0.f};
  const int srow = tid>>1;
  const int sk0  = (tid&1)*8;
  const int arow = wr*64 + (lane&15);
  const int brow = wc*64 + (lane&15);
  const int kfrag = (lane>>4)*8;
  for (int ks=0; ks<8; ++ks){
    const int kb = ks*64;
    __syncthreads();
#pragma unroll
    for (int c=0;c<4;++c){
      int k = sk0 + c*16;
      int swz = k ^ ((srow&7)<<3);
      *(uint4*)&Abf[srow*64 + swz] = *(const uint4*)(A16 + (size_t)(r0+srow)*512 + kb + k);
      *(uint4*)&Bbf[srow*64 + swz] = *(const uint4*)(W16 + (size_t)(v0+srow)*512 + kb + k);
    }
    __syncthreads();
#pragma unroll
    for (int kk=0; kk<64; kk+=32){
      v8s af[4], bf[4];
#pragma unroll
      for (int mi=0;mi<4;++mi){
        int row = arow + mi*16;
        int k = kk + kfrag;
        af[mi] = *(const v8s*)&Abf[row*64 + (k ^ ((row&7)<<3))];
      }
#pragma unroll
      for (int ni=0;ni<4;++ni){
        int row = brow + ni*16;
        int k = kk + kfrag;
        bf[ni] = *(const v8s*)&Bbf[row*64 + (k ^ ((row&7)<<3))];
      }
#pragma unroll
      for (int mi=0;mi<4;++mi)
#pragma unroll
        for (int ni=0;ni<4;++ni)
          acc[mi][ni] = __builtin_amdgcn_mfma_f32_16x16x32_bf16(af[mi], bf[ni], acc[mi][ni], 0,0,0);
    }
  }
  float bj[4];
#pragma unroll
  for (int ni=0;ni<4;++ni) bj[ni] = bv[v0 + wc*64 + ni*16 + (lane&15)];
#pragma unroll
  for (int mi=0;mi<4;++mi){
#pragma unroll
    for (int r=0;r<4;++r){
      float x0 = acc[mi][0][r]+bj[0], x1 = acc[mi][1][r]+bj[1];
      float x2 = acc[mi][2][r]+bj[2], x3 = acc[mi][3][r]+bj[3];
      float mx = fmaxf(fmaxf(x0,x1), fmaxf(x2,x3));
#pragma unroll
      for (int off=1; off<16; off<<=1) mx = fmaxf(mx, __shfl_xor(mx, off));
      float se = __expf(x0-mx)+__expf(x1-mx)+__expf(x2-mx)+__expf(x3-mx);
#pragma unroll
      for (int off=1; off<16; off<<=1) se += __shfl_xor(se, off);
      if ((lane&15)==0){
        int row = r0 + wr*64 + mi*16 + (lane>>4)*4 + r;
        int chunk = vb*2 + wc;
        size_t o = ((size_t)row*NCH + chunk)*2;
        stats[o]   = mx;
        stats[o+1] = se;
      }
    }
  }
}

// wave-per-row LSE combine over 500 chunks
__global__ void row_lse(const float* __restrict__ stats, float* __restrict__ lse){
  int r = blockIdx.x*4 + (threadIdx.x>>6);
  int lane = threadIdx.x & 63;
  const float* st = stats + (size_t)r*NCH*2;
  float M = -INFINITY;
  for (int c=lane; c<NCH; c+=64) M = fmaxf(M, st[2*c]);
#pragma unroll
  for (int off=32; off; off>>=1) M = fmaxf(M, __shfl_xor(M, off));
  float S = 0.f;
  for (int c=lane; c<NCH; c+=64) S += __expf(st[2*c]-M)*st[2*c+1];
#pragma unroll
  for (int off=32; off; off>>=1) S += __shfl_xor(S, off);
  if (lane==0) lse[r] = M + logf(S);
}

__global__ void tgt_nll(const float* __restrict__ A, const float* __restrict__ Wv,
                        const float* __restrict__ bv, const int* __restrict__ tgt,
                        const float* __restrict__ lse, float* __restrict__ nll){
  int r = blockIdx.x;         // Rn blocks of 64
  int t = r / Bn, b = r % Bn;
  int v = tgt[b*Tn + t];
  int lane = threadIdx.x;
  const float* ar = A + (size_t)r*Hn;
  const float* wr = Wv + (size_t)v*Hn;
  float acc=0.f;
  for (int k=lane;k<Hn;k+=64) acc += ar[k]*wr[k];
#pragma unroll
  for (int off=32; off>0; off>>=1) acc += __shfl_down(acc, off);
  if (lane==0) nll[r] = lse[r] - (acc + bv[v]);
}

__global__ void final_mean(const float* __restrict__ nll, float* __restrict__ out){
  __shared__ float red[256];
  float acc=0.f;
  for (int i=threadIdx.x;i<Rn;i+=256) acc += nll[i];
  red[threadIdx.x]=acc;
  __syncthreads();
  for (int off=128; off>0; off>>=1){
    if (threadIdx.x<off) red[threadIdx.x]+=red[threadIdx.x+off];
    __syncthreads();
  }
  if (threadIdx.x==0) out[0] = red[0] / (float)Rn;
}

extern "C" void kernel_launch(void* const* d_in, const int* in_sizes, int n_in,
                              void* d_out, int out_size, void* d_ws, size_t ws_size,
                              hipStream_t stream){
  (void)in_sizes; (void)n_in; (void)out_size; (void)ws_size;
  const int*   srcP  = (const int*)  d_in[0];
  const int*   tgtP  = (const int*)  d_in[1];
  const int*   lens  = (const int*)  d_in[2];
  const float* semb  = (const float*)d_in[3];
  const float* temb  = (const float*)d_in[4];
  const float* Wih_f = (const float*)d_in[5];
  const float* Whh_f = (const float*)d_in[6];
  const float* b_f   = (const float*)d_in[7];
  const float* Wih_b = (const float*)d_in[8];
  const float* Whh_b = (const float*)d_in[9];
  const float* b_b   = (const float*)d_in[10];
  const float* Wih_d = (const float*)d_in[11];
  const float* Whh_d = (const float*)d_in[12];
  const float* b_d   = (const float*)d_in[13];
  const float* Whp   = (const float*)d_in[14];
  const float* bhp   = (const float*)d_in[15];
  const float* Wcp   = (const float*)d_in[16];
  const float* bcp   = (const float*)d_in[17];
  const float* Watt  = (const float*)d_in[18];
  const float* batt  = (const float*)d_in[19];
  const float* Wcomb = (const float*)d_in[20];
  const float* bcomb = (const float*)d_in[21];
  const float* Wvoc  = (const float*)d_in[22];
  const float* bvoc  = (const float*)d_in[23];

  float* w = (float*)d_ws;
  size_t off=0;
  auto alloc=[&](size_t n){ float* p = w+off; off+=n; return p; };
  const size_t BH = (size_t)Bn*Hn;
  float* encH = alloc((size_t)Bn*Sn*2*Hn);
  float* outR = alloc((size_t)Bn*Sn*Hn);
  float* eprj = alloc((size_t)Bn*Sn*Hn);
  float* outs = alloc((size_t)Tn*Bn*Hn);
  float* Gf   = alloc((size_t)Bn*Sn*4*Hn);
  float* Gb   = alloc((size_t)Bn*Sn*4*Hn);
  float* Gdy  = alloc((size_t)Tn*Bn*4*Hn);
  float* penc = alloc((size_t)2*8*64*2048);
  float* pdec = alloc((size_t)16*64*2048);
  float* pcomb= alloc((size_t)24*64*512);
  float* small= alloc(10*BH);
  float* actx = alloc((size_t)Bn*2*Hn);
  float* lse  = alloc(Rn);
  float* nll  = alloc(Rn);
  unsigned short* A16 = (unsigned short*)alloc((size_t)Rn*Hn/2);
  int* grev = (int*)alloc(Bn*Sn);
  int* gtgt = (int*)alloc(Tn*Bn);
  // aliases (lifetime-disjoint):
  unsigned short* W16 = (unsigned short*)Gf;     // over Gf+Gb (dead after encoder loop)
  float* stats = penc;                           // over penc+pdec (dead after scans)

  float* hF0 = small + 0*BH; float* hF1 = small + 1*BH; float* cF = small + 2*BH;
  float* hB0 = small + 3*BH; float* hB1 = small + 4*BH; float* cB = small + 5*BH;
  float* dH0 = small + 6*BH; float* dH1 = small + 7*BH; float* dC = small + 8*BH;

  {
    int n4 = (int)(10*BH/4);
    zero_f4<<<(n4+255)/256, 256, 0, stream>>>((float4*)small, n4);
  }
  build_maps<<<(Bn*Sn+255)/256, 256, 0, stream>>>(srcP, tgtP, lens, grev, gtgt);

  // input-side gate precompute
  gemm128<<<dim3(16,20), 256, 0, stream>>>(semb, En, srcP, Wih_f, En, b_f, Gf, 4*Hn, En);
  gemm128<<<dim3(16,20), 256, 0, stream>>>(semb, En, grev, Wih_b, En, b_b, Gb, 4*Hn, En);
  gemm128<<<dim3(16,20), 256, 0, stream>>>(temb, En, gtgt, Wih_d, En+Hn, b_d, Gdy, 4*Hn, En);

  // encoder scans (both directions fused per step)
  float* hF[2] = {hF0, hF1};
  float* hB[2] = {hB0, hB1};
  for (int s=0;s<Sn;++s){
    enc_partial<<<dim3(16,8,2), 256, 0, stream>>>(hF[s&1], hB[s&1], Whh_f, Whh_b, penc);
    enc_reduce<<<256, 256, 0, stream>>>(penc, Gf, Gb,
        hF[s&1], hF[(s+1)&1], cF, hB[s&1], hB[(s+1)&1], cB, encH, outR, lens, s);
  }
  // Wvoc -> bf16 over dead Gf/Gb region
  cvt_bf16<<<(VTn*Hn/8 + 255)/256, 256, 0, stream>>>(Wvoc, W16, VTn*Hn/8);
  {
    int tot = Bn*Sn*(Hn/4);
    reverse_bwd<<<(tot+255)/256, 256, 0, stream>>>(outR, lens, encH);
  }
  proj_cat<<<(Bn*Hn)/256, 256, 0, stream>>>(hF0, hB0, Whp, bhp, dH0);
  proj_cat<<<(Bn*Hn)/256, 256, 0, stream>>>(cF,  cB,  Wcp, bcp, dC);
  gemm128<<<dim3(4,20), 256, 0, stream>>>(encH, 2*Hn, nullptr, Watt, 2*Hn, batt, eprj, Hn, 2*Hn);

  // decoder scan: 3 launches per step
  float* dH[2] = {dH0, dH1};
  for (int t=0;t<Tn;++t){
    float* hcur = dH[(t+1)&1];
    dec_gates<<<384, 256, 0, stream>>>(dH[t&1], Whh_d, Wih_d, pcomb, bcomb,
                                       pdec, outs, A16, t);
    dec_fused<<<Bn, 256, 0, stream>>>(pdec, Gdy, hcur, dC, eprj, encH, actx, lens, t);
    comb_partial<<<dim3(8,24), 256, 0, stream>>>(hcur, actx, Wcomb, pcomb);
  }
  comb_last<<<128, 256, 0, stream>>>(pcomb, bcomb, outs, A16);

  // vocab pipeline (bf16 MFMA)
  vocab_mfma<<<dim3(VTn/128, Rn/128), 256, 0, stream>>>(A16, W16, bvoc, stats);
  row_lse<<<Rn/4, 256, 0, stream>>>(stats, lse);
  tgt_nll<<<Rn, 64, 0, stream>>>(outs, Wvoc, bvoc, tgtP, lse, nll);
  final_mean<<<1, 256, 0, stream>>>(nll, (float*)d_out);
}

// Round 5
// 2440.386 us; speedup vs baseline: 7.0839x; 1.1286x over previous
//
#include <hip/hip_runtime.h>
#include <math.h>

#define En 256
#define Hn 512
#define Bn 64
#define Sn 40
#define Tn 40
#define VTn 32000
#define Rn (Tn*Bn)
#define NCH 500   // 32000/64 stat chunks

typedef short v8s __attribute__((ext_vector_type(8)));
typedef float v4f __attribute__((ext_vector_type(4)));
typedef _Float16 h2v __attribute__((ext_vector_type(2)));

#if defined(__has_builtin)
#  if __has_builtin(__builtin_amdgcn_fdot2)
#    define HAVE_FDOT2 1
#  endif
#endif

__device__ __forceinline__ float dot4(float4 a, float4 b){
  return a.x*b.x + a.y*b.y + a.z*b.z + a.w*b.w;
}
__device__ __forceinline__ float sigm(float x){ return 1.f/(1.f+__expf(-x)); }
__device__ __forceinline__ unsigned short f2bf(float f){
  unsigned u = __float_as_uint(f);
  unsigned r = u + 0x7FFFu + ((u>>16)&1u);
  return (unsigned short)(r>>16);
}
__device__ __forceinline__ float bf2f(unsigned short u){
  return __uint_as_float(((unsigned)u)<<16);
}
__device__ __forceinline__ unsigned pkbf(float a, float b){
  return (unsigned)f2bf(a) | ((unsigned)f2bf(b)<<16);
}
__device__ __forceinline__ unsigned pkh(float a, float b){
  _Float16 ha = (_Float16)a, hb = (_Float16)b;
  unsigned short ua = __builtin_bit_cast(unsigned short, ha);
  unsigned short ub = __builtin_bit_cast(unsigned short, hb);
  return (unsigned)ua | ((unsigned)ub<<16);
}
__device__ __forceinline__ float fd2(unsigned w, unsigned h, float c){
#ifdef HAVE_FDOT2
  return __builtin_amdgcn_fdot2(__builtin_bit_cast(h2v,w), __builtin_bit_cast(h2v,h), c, false);
#else
  h2v a = __builtin_bit_cast(h2v,w), b = __builtin_bit_cast(h2v,h);
  return c + (float)a[0]*(float)b[0] + (float)a[1]*(float)b[1];
#endif
}

// ============ prep: zero states + maps + weight converts (1 launch) ============
// ranges: 224 zero | 10 maps | 512 Whf | 512 Whb | 1024 Wd | 384 Wcomb(f16)
__global__ void prep(float* zero_base,
                     const int* __restrict__ src, const int* __restrict__ tgt,
                     const int* __restrict__ lens, int* __restrict__ grev,
                     int* __restrict__ gtgt,
                     const float* __restrict__ Whh_f, unsigned short* __restrict__ Whf16,
                     const float* __restrict__ Whh_b, unsigned short* __restrict__ Whb16,
                     const float* __restrict__ Whh_d, const float* __restrict__ Wih_d,
                     unsigned short* __restrict__ Wd16,
                     const float* __restrict__ Wcomb, unsigned short* __restrict__ Wc16){
  int blk = blockIdx.x, tid = threadIdx.x;
  if (blk < 224){
    ((float4*)zero_base)[blk*256 + tid] = make_float4(0.f,0.f,0.f,0.f);
    return;
  }
  blk -= 224;
  if (blk < 10){
    int r = blk*256 + tid;
    if (r < Bn*Sn){
      int b = r/Sn, s = r%Sn;
      int j = lens[b]-1-s;
      grev[r] = (j>=0) ? src[b*Sn+j] : -1;
      int t2 = r>>6, b2 = r&63;
      gtgt[r] = tgt[b2*Tn + t2];
    }
    return;
  }
  blk -= 10;
  if (blk < 512){
    size_t e = ((size_t)blk*256 + tid)*8;
    float4 a = *(const float4*)(Whh_f+e), b = *(const float4*)(Whh_f+e+4);
    uint4 u; u.x=pkbf(a.x,a.y); u.y=pkbf(a.z,a.w); u.z=pkbf(b.x,b.y); u.w=pkbf(b.z,b.w);
    *(uint4*)(Whf16+e) = u;
    return;
  }
  blk -= 512;
  if (blk < 512){
    size_t e = ((size_t)blk*256 + tid)*8;
    float4 a = *(const float4*)(Whh_b+e), b = *(const float4*)(Whh_b+e+4);
    uint4 u; u.x=pkbf(a.x,a.y); u.y=pkbf(a.z,a.w); u.z=pkbf(b.x,b.y); u.w=pkbf(b.z,b.w);
    *(uint4*)(Whb16+e) = u;
    return;
  }
  blk -= 512;
  if (blk < 1024){
    size_t e = ((size_t)blk*256 + tid)*8;     // [2048][1024]: k<512 Whh_d, else Wih_d cols 256+
    int row = (int)(e>>10), k = (int)(e&1023);
    const float* sp = (k<512) ? (Whh_d + (size_t)row*512 + k)
                              : (Wih_d + (size_t)row*768 + 256 + (k-512));
    float4 a = *(const float4*)sp, b = *(const float4*)(sp+4);
    uint4 u; u.x=pkbf(a.x,a.y); u.y=pkbf(a.z,a.w); u.z=pkbf(b.x,b.y); u.w=pkbf(b.z,b.w);
    *(uint4*)(Wd16+e) = u;
    return;
  }
  blk -= 1024;
  { // Wcomb -> f16, 384 blocks
    size_t e = ((size_t)blk*256 + tid)*8;
    float4 a = *(const float4*)(Wcomb+e), b = *(const float4*)(Wcomb+e+4);
    uint4 u; u.x=pkh(a.x,a.y); u.y=pkh(a.z,a.w); u.z=pkh(b.x,b.y); u.w=pkh(b.z,b.w);
    *(uint4*)(Wc16+e) = u;
  }
}

// ============ generic bf16-staging MFMA GEMM: C[M,N] = gather(A)f32 @ Bf32^T + bias ============
struct GArg {
  const float* A; const int* gth; int lda;
  const float* B; int ldb;
  const float* bias; float* C; int ldc; int K;
};
struct GArg3 { GArg a[3]; };

__global__ __launch_bounds__(256) void ggemm(GArg3 p3){
  GArg d = p3.a[blockIdx.z];
  __shared__ unsigned short Abf[128*64];
  __shared__ unsigned short Bbf[128*64];
  const int n0 = blockIdx.x*128, r0 = blockIdx.y*128;
  const int tid = threadIdx.x;
  const int w = tid>>6, lane = tid&63;
  const int wr = w>>1, wc = w&1;
  v4f acc[4][4];
#pragma unroll
  for (int i=0;i<4;++i)
#pragma unroll
    for (int j=0;j<4;++j) acc[i][j] = (v4f){0.f,0.f,0.f,0.f};
  const int srow = tid>>1, kc = (tid&1)*32;
  int ar = d.gth ? d.gth[r0+srow] : (r0+srow);
  const float* Arow = (ar>=0) ? (d.A + (size_t)ar*d.lda) : nullptr;
  const float* Brow = d.B + (size_t)(n0+srow)*d.ldb;
  for (int kb=0; kb<d.K; kb+=64){
    __syncthreads();
#pragma unroll
    for (int c=0;c<4;++c){
      int k = kc + c*8;
      int swz = k ^ ((srow&7)<<3);
      uint4 ua;
      if (Arow){
        float4 x0 = *(const float4*)(Arow+kb+k);
        float4 x1 = *(const float4*)(Arow+kb+k+4);
        ua.x=pkbf(x0.x,x0.y); ua.y=pkbf(x0.z,x0.w); ua.z=pkbf(x1.x,x1.y); ua.w=pkbf(x1.z,x1.w);
      } else ua = make_uint4(0,0,0,0);
      *(uint4*)&Abf[srow*64 + swz] = ua;
      float4 y0 = *(const float4*)(Brow+kb+k);
      float4 y1 = *(const float4*)(Brow+kb+k+4);
      uint4 ub; ub.x=pkbf(y0.x,y0.y); ub.y=pkbf(y0.z,y0.w); ub.z=pkbf(y1.x,y1.y); ub.w=pkbf(y1.z,y1.w);
      *(uint4*)&Bbf[srow*64 + swz] = ub;
    }
    __syncthreads();
#pragma unroll
    for (int kk=0; kk<64; kk+=32){
      int kfr = kk + (lane>>4)*8;
      v8s bfr[4];
#pragma unroll
      for (int ni=0;ni<4;++ni){
        int brow = wc*64 + ni*16 + (lane&15);
        bfr[ni] = *(const v8s*)&Bbf[brow*64 + (kfr ^ ((brow&7)<<3))];
      }
#pragma unroll
      for (int mi=0;mi<4;++mi){
        int arl = wr*64 + mi*16 + (lane&15);
        v8s af = *(const v8s*)&Abf[arl*64 + (kfr ^ ((arl&7)<<3))];
#pragma unroll
        for (int ni=0;ni<4;++ni)
          acc[mi][ni] = __builtin_amdgcn_mfma_f32_16x16x32_bf16(af, bfr[ni], acc[mi][ni], 0,0,0);
      }
    }
  }
#pragma unroll
  for (int ni=0;ni<4;++ni){
    int col = n0 + wc*64 + ni*16 + (lane&15);
    float bb = d.bias[col];
#pragma unroll
    for (int mi=0;mi<4;++mi)
#pragma unroll
      for (int r=0;r<4;++r){
        int row = r0 + wr*64 + mi*16 + (lane>>4)*4 + r;
        d.C[(size_t)row*d.ldc + col] = acc[mi][ni][r] + bb;
      }
  }
}

// ============ encoder step: full-K MFMA gates + LSTM, both dirs (1 launch/step) ============
// grid 64: dir = bx>>5, u-tile = bx&31 (16 u each). block rows = 4 gates x 16 u.
__global__ __launch_bounds__(256) void enc_step(
    const unsigned short* __restrict__ hf_in, unsigned short* __restrict__ hf_out,
    const unsigned short* __restrict__ hb_in, unsigned short* __restrict__ hb_out,
    float* __restrict__ cF, float* __restrict__ cB,
    const unsigned short* __restrict__ Wf16, const unsigned short* __restrict__ Wb16,
    const float* __restrict__ Gf, const float* __restrict__ Gb,
    float* __restrict__ encH, float* __restrict__ outR,
    const int* __restrict__ lens, int s){
  __shared__ unsigned short Wls[64*64];
  __shared__ unsigned short Hls[64*64];
  __shared__ float Cls[64][66];
  const int bx = blockIdx.x;
  const int dir = bx>>5;
  const int u0 = (bx&31)*16;
  const unsigned short* W16 = dir ? Wb16 : Wf16;
  const unsigned short* hin = dir ? hb_in : hf_in;
  unsigned short* hout      = dir ? hb_out : hf_out;
  float* c = dir ? cB : cF;
  const float* G = dir ? Gb : Gf;
  const int tid = threadIdx.x, w = tid>>6, lane = tid&63;
  v4f acc[4];
#pragma unroll
  for (int ni=0;ni<4;++ni) acc[ni] = (v4f){0.f,0.f,0.f,0.f};
  const int l = tid>>2;
  const int kc4 = (tid&3)*16;
  const int grow = (l>>4)*512 + u0 + (l&15);
  const unsigned short* Wrow = W16 + (size_t)grow*512;
  const unsigned short* Hrow = hin + (size_t)l*512;
  for (int kb=0; kb<512; kb+=64){
    __syncthreads();
#pragma unroll
    for (int c2=0;c2<2;++c2){
      int k = kc4 + c2*8;
      int swz = k ^ ((l&7)<<3);
      *(uint4*)&Wls[l*64+swz] = *(const uint4*)(Wrow + kb + k);
      *(uint4*)&Hls[l*64+swz] = *(const uint4*)(Hrow + kb + k);
    }
    __syncthreads();
#pragma unroll
    for (int kk=0; kk<64; kk+=32){
      int kfr = kk + (lane>>4)*8;
      int mrow = w*16 + (lane&15);
      v8s af = *(const v8s*)&Wls[mrow*64 + (kfr ^ ((mrow&7)<<3))];
#pragma unroll
      for (int ni=0;ni<4;++ni){
        int brow = ni*16 + (lane&15);
        v8s bf = *(const v8s*)&Hls[brow*64 + (kfr ^ ((brow&7)<<3))];
        acc[ni] = __builtin_amdgcn_mfma_f32_16x16x32_bf16(af, bf, acc[ni], 0,0,0);
      }
    }
  }
#pragma unroll
  for (int ni=0;ni<4;++ni)
#pragma unroll
    for (int r=0;r<4;++r)
      Cls[w*16 + (lane>>4)*4 + r][ni*16 + (lane&15)] = acc[ni][r];
  __syncthreads();
  const int u_l = tid&15, bq = tid>>4;
#pragma unroll
  for (int j=0;j<4;++j){
    int b = bq + j*16;
    size_t gidx = ((size_t)(b*Sn+s))*2048 + u0 + u_l;
    float gi = Cls[u_l][b]      + G[gidx];
    float gf = Cls[16+u_l][b]   + G[gidx+512];
    float gg = Cls[32+u_l][b]   + G[gidx+1024];
    float go = Cls[48+u_l][b]   + G[gidx+1536];
    int bu = b*512 + u0 + u_l;
    bool valid = s < lens[b];
    float cp = c[bu];
    float cn = sigm(gf)*cp + sigm(gi)*tanhf(gg);
    float hn = sigm(go)*tanhf(cn);
    c[bu] = valid ? cn : cp;
    hout[bu] = valid ? f2bf(hn) : hin[bu];
    if (dir==0) encH[((size_t)(b*Sn+s))*1024 + u0+u_l] = valid ? hn : 0.f;
    else        outR[((size_t)(b*Sn+s))*512  + u0+u_l] = valid ? hn : 0.f;
  }
}

// ============ mid: proj-h/proj-c + reverse-bwd + Wvoc cvt (1 launch) ============
// ranges: 64 proj-h | 64 proj-c | 640 reverse | 8000 Wvoc
__global__ void mid_fused(const unsigned short* __restrict__ h16f,
                          const unsigned short* __restrict__ h16b,
                          const float* __restrict__ cF, const float* __restrict__ cB,
                          const float* __restrict__ Whp, const float* __restrict__ bhp,
                          const float* __restrict__ Wcp, const float* __restrict__ bcp,
                          unsigned short* __restrict__ ho0, float* __restrict__ dC,
                          const float* __restrict__ outR, const int* __restrict__ lens,
                          float* __restrict__ encH,
                          const float* __restrict__ Wvoc, unsigned short* __restrict__ W16){
  int blk = blockIdx.x, tid = threadIdx.x;
  if (blk < 128){
    int isC = blk >= 64;
    int idx = (blk & 63)*256 + tid;
#pragma unroll
    for (int e=0;e<2;++e){
      int o = idx*2 + e;
      int b = o>>9, u = o&511;
      if (!isC){
        const float* wr = Whp + (size_t)u*1024;
        float acc = bhp[u];
        const uint4* hf4 = (const uint4*)(h16f + (size_t)b*512);
        for (int q=0;q<64;++q){
          uint4 v = hf4[q];
          unsigned uu[4] = {v.x,v.y,v.z,v.w};
#pragma unroll
          for (int i2=0;i2<4;++i2){
            acc += bf2f((unsigned short)(uu[i2]&0xFFFF))*wr[q*8+i2*2];
            acc += bf2f((unsigned short)(uu[i2]>>16))   *wr[q*8+i2*2+1];
          }
        }
        const uint4* hb4 = (const uint4*)(h16b + (size_t)b*512);
        const float* wr2 = wr + 512;
        for (int q=0;q<64;++q){
          uint4 v = hb4[q];
          unsigned uu[4] = {v.x,v.y,v.z,v.w};
#pragma unroll
          for (int i2=0;i2<4;++i2){
            acc += bf2f((unsigned short)(uu[i2]&0xFFFF))*wr2[q*8+i2*2];
            acc += bf2f((unsigned short)(uu[i2]>>16))   *wr2[q*8+i2*2+1];
          }
        }
        ho0[b*1024 + u] = f2bf(acc);
      } else {
        const float4* w4 = (const float4*)(Wcp + (size_t)u*1024);
        float acc = bcp[u];
        const float4* x1 = (const float4*)(cF + (size_t)b*512);
        const float4* x2 = (const float4*)(cB + (size_t)b*512);
        for (int q=0;q<128;++q) acc += dot4(x1[q], w4[q]);
        for (int q=0;q<128;++q) acc += dot4(x2[q], w4[128+q]);
        dC[b*512 + u] = acc;
      }
    }
    return;
  }
  blk -= 128;
  if (blk < 640){
    int e = (blk*256 + tid)*8;       // < 1,310,720
    int u = e & 511;
    int bsi = e >> 9;
    int s = bsi % Sn, b = bsi / Sn;
    int len = lens[b];
    float4 v0 = make_float4(0,0,0,0), v1 = make_float4(0,0,0,0);
    if (s < len){
      int j = len-1-s;
      const float* sp = outR + ((size_t)(b*Sn+j))*512 + u;
      v0 = *(const float4*)sp; v1 = *(const float4*)(sp+4);
    }
    float* dp = encH + ((size_t)(b*Sn+s))*1024 + 512 + u;
    *(float4*)dp = v0; *(float4*)(dp+4) = v1;
    return;
  }
  blk -= 640;
  { // Wvoc cvt, 8000 blocks
    size_t e = ((size_t)blk*256 + tid)*8;
    float4 a = *(const float4*)(Wvoc+e), b = *(const float4*)(Wvoc+e+4);
    uint4 u; u.x=pkbf(a.x,a.y); u.y=pkbf(a.z,a.w); u.z=pkbf(b.x,b.y); u.w=pkbf(b.z,b.w);
    *(uint4*)(W16+e) = u;
  }
}

// ============ decoder K_A: MFMA gates (K=1024 over [h|o]) + LSTM ============
// grid 32: u-tile (16 u). writes h(t) bf16 into ho_next h-part.
__global__ __launch_bounds__(256) void dec_gates(
    const unsigned short* __restrict__ Wd16, const unsigned short* __restrict__ ho_cur,
    unsigned short* __restrict__ ho_next, const float* __restrict__ Gdy,
    float* __restrict__ dC, int t){
  __shared__ unsigned short Wls[64*64];
  __shared__ unsigned short Hls[64*64];
  __shared__ float Cls[64][66];
  const int u0 = blockIdx.x*16;
  const int tid = threadIdx.x, w = tid>>6, lane = tid&63;
  v4f acc[4];
#pragma unroll
  for (int ni=0;ni<4;++ni) acc[ni] = (v4f){0.f,0.f,0.f,0.f};
  const int l = tid>>2;
  const int kc4 = (tid&3)*16;
  const int grow = (l>>4)*512 + u0 + (l&15);
  const unsigned short* Wrow = Wd16 + (size_t)grow*1024;
  const unsigned short* Hrow = ho_cur + (size_t)l*1024;
  for (int kb=0; kb<1024; kb+=64){
    __syncthreads();
#pragma unroll
    for (int c2=0;c2<2;++c2){
      int k = kc4 + c2*8;
      int swz = k ^ ((l&7)<<3);
      *(uint4*)&Wls[l*64+swz] = *(const uint4*)(Wrow + kb + k);
      *(uint4*)&Hls[l*64+swz] = *(const uint4*)(Hrow + kb + k);
    }
    __syncthreads();
#pragma unroll
    for (int kk=0; kk<64; kk+=32){
      int kfr = kk + (lane>>4)*8;
      int mrow = w*16 + (lane&15);
      v8s af = *(const v8s*)&Wls[mrow*64 + (kfr ^ ((mrow&7)<<3))];
#pragma unroll
      for (int ni=0;ni<4;++ni){
        int brow = ni*16 + (lane&15);
        v8s bf = *(const v8s*)&Hls[brow*64 + (kfr ^ ((brow&7)<<3))];
        acc[ni] = __builtin_amdgcn_mfma_f32_16x16x32_bf16(af, bf, acc[ni], 0,0,0);
      }
    }
  }
#pragma unroll
  for (int ni=0;ni<4;++ni)
#pragma unroll
    for (int r=0;r<4;++r)
      Cls[w*16 + (lane>>4)*4 + r][ni*16 + (lane&15)] = acc[ni][r];
  __syncthreads();
  const int u_l = tid&15, bq = tid>>4;
#pragma unroll
  for (int j=0;j<4;++j){
    int b = bq + j*16;
    size_t gidx = ((size_t)(t*Bn+b))*2048 + u0 + u_l;
    float gi = Cls[u_l][b]      + Gdy[gidx];
    float gf = Cls[16+u_l][b]   + Gdy[gidx+512];
    float gg = Cls[32+u_l][b]   + Gdy[gidx+1024];
    float go = Cls[48+u_l][b]   + Gdy[gidx+1536];
    int bu = b*512 + u0 + u_l;
    float cp = dC[bu];
    float cn = sigm(gf)*cp + sigm(gi)*tanhf(gg);
    float hn = sigm(go)*tanhf(cn);
    dC[bu] = cn;
    ho_next[b*1024 + u0 + u_l] = f2bf(hn);
  }
}

// ============ decoder K_BC: attention + combine (4 blocks/batch) ============
// grid 256: b = bx>>2, q = bx&3 (combine rows q*128..+128). writes o bf16 + A16 row.
__global__ __launch_bounds__(256) void dec_attcomb(
    unsigned short* __restrict__ ho_next, const float* __restrict__ eprj,
    const float* __restrict__ encH, const int* __restrict__ lens,
    const unsigned short* __restrict__ Wc16, const float* __restrict__ bcomb,
    unsigned short* __restrict__ A16, int t){
  const int b = blockIdx.x >> 2;
  const int q = blockIdx.x & 3;
  const int tid = threadIdx.x;
  __shared__ __align__(16) float hs[512];
  __shared__ __align__(16) float als[1024];
  __shared__ float es[Sn], sal[Sn];
  __shared__ float sinv;
  __shared__ __align__(16) unsigned int ha16[768];
  __shared__ float ps[128][2];
  for (int i=tid; i<512; i+=256) hs[i] = bf2f(ho_next[b*1024 + i]);
  __syncthreads();
  const int wv = tid>>6, lane = tid&63;
  const int len = lens[b];
  for (int si=0; si<10; ++si){
    int s2 = wv*10 + si;
    const float* pr = eprj + ((size_t)(b*Sn+s2))*512 + lane*8;
    float4 p0 = *(const float4*)pr, p1 = *(const float4*)(pr+4);
    const float* hh = hs + lane*8;
    float4 h0 = *(const float4*)hh, h1 = *(const float4*)(hh+4);
    float a = dot4(p0,h0) + dot4(p1,h1);
#pragma unroll
    for (int off=32; off; off>>=1) a += __shfl_down(a, off);
    if (lane==0) es[s2] = (s2>=1 && s2<len) ? -INFINITY : a;
  }
  __syncthreads();
  if (tid < 64){
    float e2 = (tid<Sn) ? es[tid] : -INFINITY;
    float m = e2;
#pragma unroll
    for (int off=32; off; off>>=1) m = fmaxf(m, __shfl_xor(m, off));
    float p = (tid<Sn) ? __expf(e2-m) : 0.f;
    float sum = p;
#pragma unroll
    for (int off=32; off; off>>=1) sum += __shfl_xor(sum, off);
    if (tid<Sn) sal[tid] = p;
    if (tid==0) sinv = 1.f/sum;
  }
  __syncthreads();
  float inv = sinv;
#pragma unroll
  for (int dq=0; dq<4; ++dq){
    int d = dq*256 + tid;
    float acc = 0.f;
    for (int s2=0; s2<Sn; ++s2) acc += sal[s2]*encH[((size_t)(b*Sn+s2))*1024 + d];
    als[d] = acc*inv;
  }
  __syncthreads();
  for (int p=tid; p<768; p+=256){
    int i0 = 2*p, i1 = 2*p+1;
    float x0 = (i0<512) ? hs[i0] : als[i0-512];
    float x1 = (i1<512) ? hs[i1] : als[i1-512];
    ha16[p] = pkh(x0, x1);
  }
  __syncthreads();
  const int rloc = tid & 127;
  const int kh = tid >> 7;
  const int row = q*128 + rloc;
  const uint4* wp = (const uint4*)(Wc16 + (size_t)row*1536 + kh*768);
  const uint4* hp = (const uint4*)&ha16[kh*384];
  float a0 = 0.f;
#pragma unroll 4
  for (int qq=0; qq<96; ++qq){
    uint4 wv4 = wp[qq];
    uint4 hv4 = hp[qq];
    a0 = fd2(wv4.x, hv4.x, a0);
    a0 = fd2(wv4.y, hv4.y, a0);
    a0 = fd2(wv4.z, hv4.z, a0);
    a0 = fd2(wv4.w, hv4.w, a0);
  }
  ps[rloc][kh] = a0;
  __syncthreads();
  if (tid < 128){
    int r2 = q*128 + tid;
    float O = tanhf(ps[tid][0] + ps[tid][1] + bcomb[r2]);
    unsigned short ob = f2bf(O);
    ho_next[b*1024 + 512 + r2] = ob;
    A16[((size_t)(t*Bn+b))*512 + r2] = ob;
  }
}

// ============ vocab MFMA v2: 256x128 tiles, fused per-64-col stats ============
__global__ __launch_bounds__(256,1) void vocab_mfma(
    const unsigned short* __restrict__ A16, const unsigned short* __restrict__ W16,
    const float* __restrict__ bv, float* __restrict__ stats){
  __shared__ unsigned short Abf[256*64];
  __shared__ unsigned short Bbf[128*64];
  const int vb = blockIdx.x, rb = blockIdx.y;
  const int r0 = rb*256, v0 = vb*128;
  const int tid = threadIdx.x, w = tid>>6, lane = tid&63;
  const int wr = w>>1, wc = w&1;
  v4f acc[8][4];
#pragma unroll
  for (int i=0;i<8;++i)
#pragma unroll
    for (int j=0;j<4;++j) acc[i][j] = (v4f){0.f,0.f,0.f,0.f};
  const unsigned short* Arow = A16 + (size_t)(r0+tid)*512;
  const int srow2 = tid>>1, kc2 = (tid&1)*32;
  const unsigned short* Brow = W16 + (size_t)(v0+srow2)*512;
  for (int kb=0; kb<512; kb+=64){
    __syncthreads();
#pragma unroll
    for (int c=0;c<8;++c){
      int k = c*8;
      *(uint4*)&Abf[tid*64 + (k ^ ((tid&7)<<3))] = *(const uint4*)(Arow + kb + k);
    }
#pragma unroll
    for (int c=0;c<4;++c){
      int k = kc2 + c*8;
      *(uint4*)&Bbf[srow2*64 + (k ^ ((srow2&7)<<3))] = *(const uint4*)(Brow + kb + k);
    }
    __syncthreads();
#pragma unroll
    for (int kk=0; kk<64; kk+=32){
      int kfr = kk + (lane>>4)*8;
      v8s bfr[4];
#pragma unroll
      for (int ni=0;ni<4;++ni){
        int brow = wc*64 + ni*16 + (lane&15);
        bfr[ni] = *(const v8s*)&Bbf[brow*64 + (kfr ^ ((brow&7)<<3))];
      }
#pragma unroll
      for (int mi=0;mi<8;++mi){
        int arow = wr*128 + mi*16 + (lane&15);
        v8s af = *(const v8s*)&Abf[arow*64 + (kfr ^ ((arow&7)<<3))];
#pragma unroll
        for (int ni=0;ni<4;++ni)
          acc[mi][ni] = __builtin_amdgcn_mfma_f32_16x16x32_bf16(af, bfr[ni], acc[mi][ni], 0,0,0);
      }
    }
  }
  float bj[4];
#pragma unroll
  for (int ni=0;ni<4;++ni) bj[ni] = bv[v0 + wc*64 + ni*16 + (lane&15)];
#pragma unroll
  for (int mi=0;mi<8;++mi){
#pragma unroll
    for (int r=0;r<4;++r){
      float x0 = acc[mi][0][r]+bj[0], x1 = acc[mi][1][r]+bj[1];
      float x2 = acc[mi][2][r]+bj[2], x3 = acc[mi][3][r]+bj[3];
      float mx = fmaxf(fmaxf(x0,x1), fmaxf(x2,x3));
#pragma unroll
      for (int off=1; off<16; off<<=1) mx = fmaxf(mx, __shfl_xor(mx, off));
      float se = __expf(x0-mx)+__expf(x1-mx)+__expf(x2-mx)+__expf(x3-mx);
#pragma unroll
      for (int off=1; off<16; off<<=1) se += __shfl_xor(se, off);
      if ((lane&15)==0){
        int row = r0 + wr*128 + mi*16 + (lane>>4)*4 + r;
        int chunk = vb*2 + wc;
        size_t o = ((size_t)row*NCH + chunk)*2;
        stats[o] = mx; stats[o+1] = se;
      }
    }
  }
}

// ============ tail: lse + target logit + atomic mean (1 launch) ============
__global__ void tail(const float* __restrict__ stats, const unsigned short* __restrict__ A16,
                     const float* __restrict__ Wvoc, const float* __restrict__ bvoc,
                     const int* __restrict__ gtgt, float* __restrict__ out){
  int r = blockIdx.x*4 + (threadIdx.x>>6);
  int lane = threadIdx.x & 63;
  const float* st = stats + (size_t)r*NCH*2;
  float M = -INFINITY;
  for (int c=lane; c<NCH; c+=64) M = fmaxf(M, st[2*c]);
#pragma unroll
  for (int off=32; off; off>>=1) M = fmaxf(M, __shfl_xor(M, off));
  float S = 0.f;
  for (int c=lane; c<NCH; c+=64) S += __expf(st[2*c]-M)*st[2*c+1];
#pragma unroll
  for (int off=32; off; off>>=1) S += __shfl_xor(S, off);
  int v = gtgt[r];
  int k = lane*8;
  uint4 a4 = *(const uint4*)(A16 + (size_t)r*512 + k);
  const float* wvp = Wvoc + (size_t)v*512 + k;
  float4 w0 = *(const float4*)wvp, w1 = *(const float4*)(wvp+4);
  unsigned uu[4] = {a4.x, a4.y, a4.z, a4.w};
  float dot = 0.f;
  dot += bf2f((unsigned short)(uu[0]&0xFFFF))*w0.x + bf2f((unsigned short)(uu[0]>>16))*w0.y;
  dot += bf2f((unsigned short)(uu[1]&0xFFFF))*w0.z + bf2f((unsigned short)(uu[1]>>16))*w0.w;
  dot += bf2f((unsigned short)(uu[2]&0xFFFF))*w1.x + bf2f((unsigned short)(uu[2]>>16))*w1.y;
  dot += bf2f((unsigned short)(uu[3]&0xFFFF))*w1.z + bf2f((unsigned short)(uu[3]>>16))*w1.w;
#pragma unroll
  for (int off=32; off; off>>=1) dot += __shfl_down(dot, off);
  if (lane==0){
    float lse = M + logf(S);
    float nll = lse - (dot + bvoc[v]);
    atomicAdd(out, nll * (1.0f/(float)Rn));
  }
}

extern "C" void kernel_launch(void* const* d_in, const int* in_sizes, int n_in,
                              void* d_out, int out_size, void* d_ws, size_t ws_size,
                              hipStream_t stream){
  (void)in_sizes; (void)n_in; (void)out_size; (void)ws_size;
  const int*   srcP  = (const int*)  d_in[0];
  const int*   tgtP  = (const int*)  d_in[1];
  const int*   lens  = (const int*)  d_in[2];
  const float* semb  = (const float*)d_in[3];
  const float* temb  = (const float*)d_in[4];
  const float* Wih_f = (const float*)d_in[5];
  const float* Whh_f = (const float*)d_in[6];
  const float* b_f   = (const float*)d_in[7];
  const float* Wih_b = (const float*)d_in[8];
  const float* Whh_b = (const float*)d_in[9];
  const float* b_b   = (const float*)d_in[10];
  const float* Wih_d = (const float*)d_in[11];
  const float* Whh_d = (const float*)d_in[12];
  const float* b_d   = (const float*)d_in[13];
  const float* Whp   = (const float*)d_in[14];
  const float* bhp   = (const float*)d_in[15];
  const float* Wcp   = (const float*)d_in[16];
  const float* bcp   = (const float*)d_in[17];
  const float* Watt  = (const float*)d_in[18];
  const float* batt  = (const float*)d_in[19];
  const float* Wcomb = (const float*)d_in[20];
  const float* bcomb = (const float*)d_in[21];
  const float* Wvoc  = (const float*)d_in[22];
  const float* bvoc  = (const float*)d_in[23];

  float* w = (float*)d_ws;
  size_t off = 0;
  auto alloc = [&](size_t n){ float* p = w + off; off += n; return p; };
  float* encH = alloc(2621440);          // [2560][1024]; stats alias after decoder
  float* outR = alloc(1310720);
  float* eprj = alloc(1310720);
  float* Gf   = alloc(5242880);          // Gf+Gb region aliased by W16 after encoder
  float* Gb   = alloc(5242880);
  float* Gdy  = alloc(5242880);
  unsigned short* A16   = (unsigned short*)alloc(655360);
  unsigned short* Whf16 = (unsigned short*)alloc(524288);
  unsigned short* Whb16 = (unsigned short*)alloc(524288);
  unsigned short* Wd16  = (unsigned short*)alloc(1048576);
  unsigned short* Wc16  = (unsigned short*)alloc(393216);
  float* zero_base = w + off;            // small-state region, zeroed by prep (229376 words)
  float* cF = alloc(32768);
  float* cB = alloc(32768);
  float* dC = alloc(32768);
  unsigned short* h16f[2] = {(unsigned short*)alloc(16384), (unsigned short*)alloc(16384)};
  unsigned short* h16b[2] = {(unsigned short*)alloc(16384), (unsigned short*)alloc(16384)};
  unsigned short* ho[2]   = {(unsigned short*)alloc(32768), (unsigned short*)alloc(32768)};
  int* grev = (int*)alloc(2560);
  int* gtgt = (int*)alloc(2560);
  unsigned short* W16 = (unsigned short*)Gf;   // 16.38M bf16 over Gf+Gb (dead post-encoder)
  float* stats = encH;                          // 2.56M f32 over encH (dead post-decoder)

  hipMemsetAsync(d_out, 0, sizeof(float), stream);
  prep<<<2666, 256, 0, stream>>>(zero_base, srcP, tgtP, lens, grev, gtgt,
                                 Whh_f, Whf16, Whh_b, Whb16, Whh_d, Wih_d, Wd16,
                                 Wcomb, Wc16);
  {
    GArg3 g;
    g.a[0] = GArg{semb, srcP, En, Wih_f, En,  b_f, Gf,  2048, En};
    g.a[1] = GArg{semb, grev, En, Wih_b, En,  b_b, Gb,  2048, En};
    g.a[2] = GArg{temb, gtgt, En, Wih_d, 768, b_d, Gdy, 2048, En};
    ggemm<<<dim3(16,20,3), 256, 0, stream>>>(g);
  }
  for (int s=0; s<Sn; ++s)
    enc_step<<<64, 256, 0, stream>>>(h16f[s&1], h16f[(s+1)&1], h16b[s&1], h16b[(s+1)&1],
                                     cF, cB, Whf16, Whb16, Gf, Gb, encH, outR, lens, s);
  mid_fused<<<8768, 256, 0, stream>>>(h16f[0], h16b[0], cF, cB, Whp, bhp, Wcp, bcp,
                                      ho[0], dC, outR, lens, encH, Wvoc, W16);
  {
    GArg3 g;
    g.a[0] = GArg{encH, nullptr, 1024, Watt, 1024, batt, eprj, 512, 1024};
    g.a[1] = g.a[0]; g.a[2] = g.a[0];
    ggemm<<<dim3(4,20,1), 256, 0, stream>>>(g);
  }
  for (int t=0; t<Tn; ++t){
    dec_gates<<<32, 256, 0, stream>>>(Wd16, ho[t&1], ho[(t+1)&1], Gdy, dC, t);
    dec_attcomb<<<256, 256, 0, stream>>>(ho[(t+1)&1], eprj, encH, lens, Wc16, bcomb, A16, t);
  }
  vocab_mfma<<<dim3(VTn/128, Rn/256), 256, 0, stream>>>(A16, W16, bvoc, stats);
  tail<<<Rn/4, 256, 0, stream>>>(stats, A16, Wvoc, bvoc, gtgt, (float*)d_out);
}